// Round 10
// baseline (194.038 us; speedup 1.0000x reference)
//
#include <hip/hip_runtime.h>
#include <hip/hip_bf16.h>
#include <math.h>

typedef __bf16 bf16;
typedef __bf16 bf16x4 __attribute__((ext_vector_type(4)));
typedef __bf16 bf16x8 __attribute__((ext_vector_type(8)));
typedef float floatx4 __attribute__((ext_vector_type(4)));

#define HIDDEN 1024
#define NHEADS 16
#define HDIM 64
#define TSEQ 2048
#define NBATCH 2
#define MTOT (NBATCH * TSEQ) /* 4096 */

// ---- async 16B global->LDS. lds addr must be wave-uniform base + lane*16. ----
__device__ inline void glds16(bf16* lds, const bf16* g)
{
  __builtin_amdgcn_global_load_lds(
      (const __attribute__((address_space(1))) unsigned int*)g,
      (__attribute__((address_space(3))) unsigned int*)lds, 16, 0, 0);
}

// ======================================================================
// prep: cvt x (blocks 0..2047) + cvt qkv_w (blocks 2048..3583)
//       + rope cos/sin table [TSEQ][32] float2 (blocks 3584..3647)
// ======================================================================
__global__ __launch_bounds__(256) void prep_kernel(
    const float* __restrict__ x, bf16* __restrict__ xb,
    const float* __restrict__ qkv_w, bf16* __restrict__ qkv_wb,
    float2* __restrict__ rope)
{
  const int bid = blockIdx.x;
  if (bid >= 3584) {
    const int e0 = ((bid - 3584) * 256 + threadIdx.x) * 4;
    const int t = e0 >> 5;
    const int d2 = e0 & 31;
#pragma unroll
    for (int j = 0; j < 4; j++) {
      const float inv = exp2f((float)(d2 + j) * -0.41524100f);
      float s, c;
      sincosf((float)t * inv, &s, &c);
      rope[e0 + j] = make_float2(c, s);
    }
    return;
  }
  const float* src = (bid < 2048) ? x : qkv_w;
  bf16* dst = (bid < 2048) ? xb : qkv_wb;
  const int i = (((bid < 2048) ? bid : bid - 2048) * 256 + threadIdx.x) * 8;
  const floatx4 u = *(const floatx4*)(src + i);
  const floatx4 v = *(const floatx4*)(src + i + 4);
  bf16x8 r;
#pragma unroll
  for (int j = 0; j < 4; j++) { r[j] = (bf16)u[j]; r[4 + j] = (bf16)v[j]; }
  *(bf16x8*)(dst + i) = r;
}

// ======================================================================
// f32 -> bf16 bulk convert (out_w, after attn frees the Vt region)
// ======================================================================
__global__ __launch_bounds__(256) void cvt_f32_bf16(
    const float* __restrict__ src, bf16* __restrict__ dst, int n)
{
  const int i = (blockIdx.x * 256 + threadIdx.x) * 8;
  if (i >= n) return;
  const floatx4 u = *(const floatx4*)(src + i);
  const floatx4 v = *(const floatx4*)(src + i + 4);
  bf16x8 r;
#pragma unroll
  for (int j = 0; j < 4; j++) { r[j] = (bf16)u[j]; r[4 + j] = (bf16)v[j]; }
  *(bf16x8*)(dst + i) = r;
}

// ======================================================================
// gemm_qkv r10 — BM=128, BN=256, BK=64, grid 384 (>= 256 CUs; the r5-r9
// 256x256 grid of 192 left 64 CUs idle = hard 25% cap).  8 waves = 2M x
// 4N, per-wave 64x64 (acc[4][4]); "wave = one head" invariant kept.
// LDS 96 KB: As[2 dbuf][2 kh][128*32] + Bs[2][2][256*32].
// Schedule: 2 phases per K-tile, each {8 ds_read || 3 glds (A:1,B:2)}
// -> vmcnt(3) -> barrier -> setprio 16 MFMA -> barrier.  Each phase's
// counted wait vouches the NEXT phase's data (ledger re-derived r10);
// tail drains vmcnt(0) at P0.  Zero-conflict XOR swizzle unchanged.
// XCD chunking: 8 rects of 8by x 6bx on the (32 x 12) grid.
// Epilogue: fused RoPE (Q/K) + transposed V store (b,h,d,t).
// ======================================================================
__global__ __launch_bounds__(512, 2) void gemm_qkv(
    const bf16* __restrict__ A, const bf16* __restrict__ W,
    const float* __restrict__ bias, const float2* __restrict__ rope,
    bf16* __restrict__ Qb, bf16* __restrict__ Kb, bf16* __restrict__ Vt,
    int M, int N, int K)
{
  __shared__ bf16 As[2][2][128 * 32];
  __shared__ bf16 Bs[2][2][256 * 32];

  const int tid  = threadIdx.x;
  const int lane = tid & 63;
  const int wv   = tid >> 6;          // 0..7
  const int quad = lane >> 4;
  const int l16  = lane & 15;
  const int wm   = (wv >> 2) * 64;    // wave M-group (2 x 64 rows)
  const int wn   = (wv & 3) * 64;     // wave N-slot (4 x 64 cols) = one head

  // XCD-chunked swizzle: 8 rects of 8by x 6bx tiling the (32 x 12) grid
  const int f   = blockIdx.x;
  const int xcd = f & 7;
  const int rr  = f >> 3;                    // 0..47
  const int bx  = (xcd & 1) * 6 + rr % 6;    // 0..11
  const int by  = (xcd >> 1) * 8 + rr / 6;   // 0..31
  const int m0 = by * 128;
  const int n0 = bx * 256;

  const int srow = lane >> 2;                               // 0..15
  const int scol = ((lane & 3) ^ ((lane >> 3) & 3)) * 8;    // XOR-swz src granule
  const int qsw  = (quad ^ ((l16 >> 1) & 3)) * 8;           // matching read swz

  const bf16* gaBase = A + (size_t)(m0 + wv * 16 + srow) * K + scol;
  const bf16* gbBase = W + (size_t)(n0 + wv * 16 + srow) * K + scol;
  const int ldst = wv * 512 + lane * 8;   // 512 thr x 16B = 8 KB (one half-tile of A)

#define STG_A(d, kh, kcol)                                                   \
  glds16(&As[d][kh][ldst], gaBase + (kcol));
#define STG_B(d, kh, kcol)                                                   \
  glds16(&Bs[d][kh][ldst],        gbBase + (kcol));                          \
  glds16(&Bs[d][kh][ldst + 4096], gbBase + (size_t)128 * K + (kcol));

#define RD_PH(d, kh)                                                         \
  _Pragma("unroll") for (int i = 0; i < 4; i++)                              \
    af[i] = *(const bf16x8*)(&As[d][kh][(wm + i * 16 + l16) * 32 + qsw]);    \
  _Pragma("unroll") for (int j = 0; j < 4; j++)                              \
    bq[j] = *(const bf16x8*)(&Bs[d][kh][(wn + j * 16 + l16) * 32 + qsw]);

#define MM_PH()                                                              \
  _Pragma("unroll") for (int i = 0; i < 4; i++)                              \
    _Pragma("unroll") for (int j = 0; j < 4; j++)                            \
      acc[i][j] = __builtin_amdgcn_mfma_f32_16x16x32_bf16(                   \
          af[i], bq[j], acc[i][j], 0, 0, 0);

  floatx4 acc[4][4];
#pragma unroll
  for (int i = 0; i < 4; i++)
#pragma unroll
    for (int j = 0; j < 4; j++) acc[i][j] = (floatx4){0.f, 0.f, 0.f, 0.f};

  // prologue: stage tile 0 (both K-halves) into buf 0
  STG_A(0, 0, 0); STG_B(0, 0, 0);
  STG_A(0, 1, 32); STG_B(0, 1, 32);
  asm volatile("s_waitcnt vmcnt(3)" ::: "memory");   // tile0 kh0 landed
  __builtin_amdgcn_s_barrier();

  const int nt = K >> 6;   // 16
#pragma unroll 1
  for (int t = 0; t < nt; t++) {
    const int c = t & 1;
    const int kn = (t + 1) * 64;
    const bool more = (t + 1 < nt);
    bf16x8 af[4], bq[4];

    // ---- P0: consume (t, kh0); stage (t+1, kh0); vouch (t, kh1) ----
    RD_PH(c, 0);
    if (more) {
      STG_A(c ^ 1, 0, kn); STG_B(c ^ 1, 0, kn);
      asm volatile("s_waitcnt vmcnt(3)" ::: "memory");
    } else {
      asm volatile("s_waitcnt vmcnt(0)" ::: "memory");
    }
    __builtin_amdgcn_s_barrier();
    __builtin_amdgcn_s_setprio(1); MM_PH(); __builtin_amdgcn_s_setprio(0);
    __builtin_amdgcn_s_barrier();

    // ---- P1: consume (t, kh1); stage (t+1, kh1); vouch (t+1, kh0) ----
    RD_PH(c, 1);
    if (more) {
      STG_A(c ^ 1, 1, kn + 32); STG_B(c ^ 1, 1, kn + 32);
      asm volatile("s_waitcnt vmcnt(3)" ::: "memory");
    }
    __builtin_amdgcn_s_barrier();
    __builtin_amdgcn_s_setprio(1); MM_PH(); __builtin_amdgcn_s_setprio(0);
    __builtin_amdgcn_s_barrier();
  }

  // ---- epilogue ----
  const int sect = n0 >> 10;                 // 0 = Q, 1 = K, 2 = V (256 | 1024)
  const int hw   = ((n0 & 1023) + wn) >> 6;  // head for this wave

  float bs[4];
#pragma unroll
  for (int j = 0; j < 4; j++) bs[j] = bias[n0 + wn + j * 16 + l16];

  if (sect < 2) {
    bf16* dst = sect ? Kb : Qb;
#pragma unroll
    for (int i = 0; i < 4; i++) {
      const int gmBase = m0 + wm + i * 16 + quad * 4;
#pragma unroll
      for (int r = 0; r < 4; r++) {
        const int gm = gmBase + r;
        const int b_ = gm >> 11, t = gm & 2047;
        const size_t rowbase = ((size_t)(b_ * NHEADS + hw) * TSEQ + t) * HDIM;
        const float2 cs0 = rope[t * 32 + l16];
        const float2 cs1 = rope[t * 32 + 16 + l16];
        const float x1a = acc[i][0][r] + bs[0];   // d = l16
        const float x2a = acc[i][2][r] + bs[2];   // d = l16 + 32
        const float x1b = acc[i][1][r] + bs[1];   // d = 16 + l16
        const float x2b = acc[i][3][r] + bs[3];   // d = 48 + l16
        dst[rowbase + l16]      = (bf16)(x1a * cs0.x - x2a * cs0.y);
        dst[rowbase + 32 + l16] = (bf16)(x1a * cs0.y + x2a * cs0.x);
        dst[rowbase + 16 + l16] = (bf16)(x1b * cs1.x - x2b * cs1.y);
        dst[rowbase + 48 + l16] = (bf16)(x1b * cs1.y + x2b * cs1.x);
      }
    }
  } else {
    // V: store transposed -> Vt[((b*16+h)*64 + d) * TSEQ + t], 8B packed over r
#pragma unroll
    for (int j = 0; j < 4; j++) {
      const int d = j * 16 + l16;
#pragma unroll
      for (int i = 0; i < 4; i++) {
        const int gmBase = m0 + wm + i * 16 + quad * 4;
        const int b_ = gmBase >> 11, t0 = gmBase & 2047;
        bf16x4 vv;
#pragma unroll
        for (int r = 0; r < 4; r++) vv[r] = (bf16)(acc[i][j][r] + bs[j]);
        *(bf16x4*)(Vt + ((size_t)((b_ * NHEADS + hw) * HDIM + d)) * TSEQ + t0) = vv;
      }
    }
  }
}

// ======================================================================
// gemm_out: 128x64 tile, grid 512 = 2 blocks/CU (FROZEN, r4 version).
// ======================================================================
__global__ __launch_bounds__(256) void gemm_out(
    const bf16* __restrict__ A, const bf16* __restrict__ W,
    const float* __restrict__ bias, float* __restrict__ C,
    int M, int N, int K)
{
  __shared__ bf16 As2[3][128 * 32];
  __shared__ bf16 Bs2[3][64 * 32];

  const int tid  = threadIdx.x;
  const int lane = tid & 63;
  const int wv   = tid >> 6;
  const int quad = lane >> 4;
  const int l16  = lane & 15;

  const int f   = blockIdx.x;
  const int xcd = f & 7;
  const int rr  = f >> 3;
  const int bx  = (xcd & 1) * 8 + (rr & 7);
  const int by  = (xcd >> 1) * 8 + (rr >> 3);
  const int m0 = by * 128;
  const int n0 = bx * 64;
  const int wm = wv * 32;

  const int srow = lane >> 2;
  const int scol = ((lane & 3) ^ ((lane >> 3) & 3)) * 8;
  const int qsw  = (quad ^ ((l16 >> 1) & 3)) * 8;

  const bf16* ga0 = A + (size_t)(m0 + wv * 32 + srow) * K + scol;
  const bf16* gb0 = W + (size_t)(n0 + wv * 16 + srow) * K + scol;

  floatx4 acc[2][4];
#pragma unroll
  for (int i = 0; i < 2; i++)
#pragma unroll
    for (int j = 0; j < 4; j++) acc[i][j] = (floatx4){0.f, 0.f, 0.f, 0.f};

#define STAGE_O(buf, kk)                                                    \
  glds16(&As2[buf][(wv * 32) * 32], ga0 + (kk));                            \
  glds16(&As2[buf][(wv * 32 + 16) * 32], ga0 + (size_t)16 * K + (kk));      \
  glds16(&Bs2[buf][(wv * 16) * 32], gb0 + (kk));

#define COMPUTE_O(buf)                                                      \
  {                                                                         \
    bf16x8 af[2], bfr[4];                                                   \
    _Pragma("unroll") for (int i = 0; i < 2; i++)                           \
        af[i] = *(const bf16x8*)(&As2[buf][(wm + i * 16 + l16) * 32 + qsw]);\
    _Pragma("unroll") for (int j = 0; j < 4; j++)                           \
        bfr[j] = *(const bf16x8*)(&Bs2[buf][(j * 16 + l16) * 32 + qsw]);    \
    _Pragma("unroll") for (int i = 0; i < 2; i++)                           \
        _Pragma("unroll") for (int j = 0; j < 4; j++)                       \
            acc[i][j] = __builtin_amdgcn_mfma_f32_16x16x32_bf16(            \
                af[i], bfr[j], acc[i][j], 0, 0, 0);                         \
  }

  STAGE_O(0, 0);
  STAGE_O(1, 32);
  int cur = 0;
  const int nsteps = K / 32;
#pragma unroll 1
  for (int t = 0; t < nsteps - 1; t++) {
    asm volatile("s_waitcnt vmcnt(3)" ::: "memory");
    __builtin_amdgcn_s_barrier();
    if (t + 2 < nsteps) {
      const int nb = (cur >= 1) ? cur - 1 : cur + 2;
      STAGE_O(nb, (t + 2) * 32);
    }
    COMPUTE_O(cur);
    cur = (cur == 2) ? 0 : cur + 1;
  }
  asm volatile("s_waitcnt vmcnt(0)" ::: "memory");
  __builtin_amdgcn_s_barrier();
  COMPUTE_O(cur);

#pragma unroll
  for (int i = 0; i < 2; i++) {
    const int gmBase = m0 + wm + i * 16 + quad * 4;
#pragma unroll
    for (int j = 0; j < 4; j++) {
      const int gn = n0 + j * 16 + l16;
      const float bsv = bias[gn];
#pragma unroll
      for (int r = 0; r < 4; r++)
        C[(size_t)(gmBase + r) * N + gn] = acc[i][j][r] + bsv;
    }
  }
}

// ---- XOR granule swizzle for staging (reads lane-linear, conflict-free) ----
__device__ inline int swz(int g) { return (g & ~7) | ((g ^ (g >> 3) ^ (g >> 6)) & 7); }

// ======================================================================
// Flash attention v7 (REVERTED to r6 best-measured): 512 blocks x 512
// thr, key-split wave groups, double-buffered K/V LDS, one barrier per
// 64-key chunk, cross-group reduce via LDS scratch, balanced pairing
// {31-p, p}.  r7-r9 variants (128-key chunks, 1-qt blocks) were null or
// regressed: occupancy 2x'd with MfmaUtil/VALUBusy unchanged -> not the
// gate.  Plateau ~40 us; escape = full in-register-softmax restructure.
// ======================================================================
__global__ __launch_bounds__(512) void attn_kernel(
    const bf16* __restrict__ Q, const bf16* __restrict__ K,
    const bf16* __restrict__ Vt, bf16* __restrict__ O,
    const int* __restrict__ ids, const int* __restrict__ gidx)
{
  __shared__ bf16 Ks[2][4096];
  __shared__ bf16 Vs[2][4096];
  __shared__ int flags[8];

  const int tid  = threadIdx.x;
  const int lane = tid & 63;
  const int wv   = tid >> 6;    // 0..7
  const int gg   = wv >> 2;     // key-half group
  const int w4   = wv & 3;      // row group (16 q-rows)
  const int quad = lane >> 4;
  const int l16  = lane & 15;

  const int xcd = blockIdx.x & 7;
  const int j   = blockIdx.x >> 3;
  const int bh  = xcd * 4 + (j >> 4);
  const int p   = j & 15;
  const int b  = bh >> 4;
  const int h  = bh & 15;

  const bf16* Qp = Q + (size_t)bh * TSEQ * HDIM;
  const bf16* Kp = K + (size_t)bh * TSEQ * HDIM;
  const bf16* Vp = Vt + (size_t)bh * HDIM * TSEQ;

  const int rK2 = tid >> 3, dcK = tid & 7;
  const int rKl = rK2 & 31, khi = rK2 >> 5;
  const int gk = ((rKl >> 2) & 1) * 128 + (dcK >> 2) * 64 +
                 ((dcK & 3) * 16 + (((rKl >> 3) << 2) | (rKl & 3)));
  const int kd = swz(gk + khi * 256) * 8;
  const int dV = tid >> 3, uV = tid & 7;
  const int gv = (uV >> 2) * 256 + (dV >> 4) * 64 + ((uV & 3) * 16 + (dV & 15));
  const int vd = swz(gv) * 8;

  const int g0v = gidx[0], g1v = gidx[1], g2v = gidx[2];

#pragma unroll
  for (int ph = 0; ph < 2; ph++) {
    const int qt = ph ? p : (31 - p);
    const int q0 = qt * 64 + w4 * 16;

    const bf16x8 qf0 = *(const bf16x8*)(Qp + (size_t)(q0 + l16) * HDIM + quad * 8);
    const bf16x8 qf1 = *(const bf16x8*)(Qp + (size_t)(q0 + l16) * HDIM + 32 + quad * 8);

    const int myq = q0 + l16;
    const int myid = ids[b * TSEQ + myq];
    const int gl = (myid == g0v) | (myid == g1v) | (myid == g2v);
    flags[wv] = __any(gl);
    __syncthreads();
    int anyg = 0;
#pragma unroll
    for (int i2 = 0; i2 < 8; i2++) anyg |= flags[i2];
    const int kmax = anyg ? TSEQ : (qt * 64 + 64);

    float lsum = 0.f;
    floatx4 o[4];
#pragma unroll
    for (int nt = 0; nt < 4; nt++) o[nt] = (floatx4){0.f, 0.f, 0.f, 0.f};

    bf16x8 kA = *(const bf16x8*)(Kp + tid * 8);
    bf16x8 vA = *(const bf16x8*)(Vp + (size_t)dV * TSEQ + uV * 8);

    for (int k0 = 0; k0 < kmax; k0 += 64) {
      bf16* KsB = Ks[(k0 >> 6) & 1];
      bf16* VsB = Vs[(k0 >> 6) & 1];
      *(bf16x8*)(KsB + kd) = kA;
      *(bf16x8*)(VsB + vd) = vA;
      __syncthreads();

      if (k0 + 64 < kmax) {
        kA = *(const bf16x8*)(Kp + (size_t)(k0 + 64) * HDIM + tid * 8);
        vA = *(const bf16x8*)(Vp + (size_t)dV * TSEQ + k0 + 64 + uV * 8);
      }

      const int kb = k0 + gg * 32;
      const int rb = gg * 256 + lane;
      const bf16x8 a00 = *(const bf16x8*)(KsB + swz(rb) * 8);
      const bf16x8 a01 = *(const bf16x8*)(KsB + swz(rb + 64) * 8);
      const bf16x8 a10 = *(const bf16x8*)(KsB + swz(rb + 128) * 8);
      const bf16x8 a11 = *(const bf16x8*)(KsB + swz(rb + 192) * 8);
      floatx4 s0 = (floatx4){0.f, 0.f, 0.f, 0.f};
      floatx4 s1 = (floatx4){0.f, 0.f, 0.f, 0.f};
      s0 = __builtin_amdgcn_mfma_f32_16x16x32_bf16(a00, qf0, s0, 0, 0, 0);
      s0 = __builtin_amdgcn_mfma_f32_16x16x32_bf16(a01, qf1, s0, 0, 0, 0);
      s1 = __builtin_amdgcn_mfma_f32_16x16x32_bf16(a10, qf0, s1, 0, 0, 0);
      s1 = __builtin_amdgcn_mfma_f32_16x16x32_bf16(a11, qf1, s1, 0, 0, 0);

      bf16x8 pf;
#pragma unroll
      for (int r = 0; r < 4; r++) {
        const int key0 = kb + quad * 8 + r;
        const int key1 = key0 + 4;
        const float p0 = (gl || key0 <= myq) ? __expf(s0[r] * 0.125f) : 0.f;
        const float p1 = (gl || key1 <= myq) ? __expf(s1[r] * 0.125f) : 0.f;
        lsum += p0 + p1;
        pf[r]     = (bf16)p0;
        pf[4 + r] = (bf16)p1;
      }

#pragma unroll
      for (int nt = 0; nt < 4; nt++) {
        const bf16x8 vf = *(const bf16x8*)(VsB + swz(gg * 256 + nt * 64 + lane) * 8);
        o[nt] = __builtin_amdgcn_mfma_f32_16x16x32_bf16(pf, vf, o[nt], 0, 0, 0);
      }
    }

    lsum += __shfl_xor(lsum, 16);
    lsum += __shfl_xor(lsum, 32);

    __syncthreads();
    float* osc = (float*)Ks;
    float* lsc = (float*)Vs;
    const int rbase = (w4 * 64 + lane) * 16;
    if (gg == 1) {
#pragma unroll
      for (int nt = 0; nt < 4; nt++)
        *(floatx4*)&osc[rbase + ((nt ^ (lane & 3)) * 4)] = o[nt];
      lsc[w4 * 64 + lane] = lsum;
    }
    __syncthreads();
    if (gg == 0) {
      lsum += lsc[w4 * 64 + lane];
#pragma unroll
      for (int nt = 0; nt < 4; nt++)
        o[nt] += *(const floatx4*)&osc[rbase + ((nt ^ (lane & 3)) * 4)];

#pragma unroll
      for (int r = 0; r < 4; r++) {
        const float inv = 1.0f / __shfl(lsum, quad * 4 + r);
        const int q = q0 + quad * 4 + r;
        const size_t rowoff = ((size_t)b * TSEQ + q) * HIDDEN + h * HDIM;
#pragma unroll
        for (int nt = 0; nt < 4; nt++)
          O[rowoff + nt * 16 + l16] = (bf16)(o[nt][r] * inv);
      }
    }
    __syncthreads();
  }
}

// ======================================================================
extern "C" void kernel_launch(void* const* d_in, const int* in_sizes, int n_in,
                              void* d_out, int out_size, void* d_ws, size_t ws_size,
                              hipStream_t stream)
{
  const float* x     = (const float*)d_in[0];
  const int*   ids   = (const int*)d_in[1];
  const float* qkv_w = (const float*)d_in[2];
  const float* qkv_b = (const float*)d_in[3];
  const float* out_w = (const float*)d_in[4];
  const float* out_b = (const float*)d_in[5];
  const int*   gidx  = (const int*)d_in[6];
  float* out = (float*)d_out;

  char* ws = (char*)d_ws;
  bf16* Q      = (bf16*)(ws);
  bf16* Kb     = (bf16*)(ws + (size_t)(8u << 20));
  bf16* Vt     = (bf16*)(ws + (size_t)(16u << 20));
  bf16* slot24 = (bf16*)(ws + (size_t)(24u << 20));
  bf16* xb     = slot24;
  bf16* O      = slot24;
  bf16* out_wb = (bf16*)(ws + (size_t)(16u << 20));
  bf16* qkv_wb = (bf16*)d_out;
  float2* rope = (float2*)((char*)d_out + (size_t)(6u << 20));

  prep_kernel<<<3648, 256, 0, stream>>>(x, xb, qkv_w, qkv_wb, rope);
  gemm_qkv<<<384, 512, 0, stream>>>(
      xb, qkv_wb, qkv_b, rope, Q, Kb, Vt, MTOT, 3 * HIDDEN, HIDDEN);
  attn_kernel<<<512, 512, 0, stream>>>(Q, Kb, Vt, O, ids, gidx);
  cvt_f32_bf16<<<512, 256, 0, stream>>>(out_w, out_wb, HIDDEN * HIDDEN);
  gemm_out<<<512, 256, 0, stream>>>(
      O, out_wb, out_b, out, MTOT, HIDDEN, HIDDEN);
}

// Round 11
// 181.942 us; speedup vs baseline: 1.0665x; 1.0665x over previous
//
#include <hip/hip_runtime.h>
#include <hip/hip_bf16.h>
#include <math.h>

typedef __bf16 bf16;
typedef __bf16 bf16x4 __attribute__((ext_vector_type(4)));
typedef __bf16 bf16x8 __attribute__((ext_vector_type(8)));
typedef float floatx4 __attribute__((ext_vector_type(4)));

#define HIDDEN 1024
#define NHEADS 16
#define HDIM 64
#define TSEQ 2048
#define NBATCH 2
#define MTOT (NBATCH * TSEQ) /* 4096 */

// ---- async 16B global->LDS. lds addr must be wave-uniform base + lane*16. ----
__device__ inline void glds16(bf16* lds, const bf16* g)
{
  __builtin_amdgcn_global_load_lds(
      (const __attribute__((address_space(1))) unsigned int*)g,
      (__attribute__((address_space(3))) unsigned int*)lds, 16, 0, 0);
}

// ======================================================================
// prep: cvt x (blocks 0..2047) + cvt qkv_w (blocks 2048..3583)
//       + rope cos/sin table [TSEQ][32] float2 (blocks 3584..3647)
// ======================================================================
__global__ __launch_bounds__(256) void prep_kernel(
    const float* __restrict__ x, bf16* __restrict__ xb,
    const float* __restrict__ qkv_w, bf16* __restrict__ qkv_wb,
    float2* __restrict__ rope)
{
  const int bid = blockIdx.x;
  if (bid >= 3584) {
    const int e0 = ((bid - 3584) * 256 + threadIdx.x) * 4;
    const int t = e0 >> 5;
    const int d2 = e0 & 31;
#pragma unroll
    for (int j = 0; j < 4; j++) {
      const float inv = exp2f((float)(d2 + j) * -0.41524100f);
      float s, c;
      sincosf((float)t * inv, &s, &c);
      rope[e0 + j] = make_float2(c, s);
    }
    return;
  }
  const float* src = (bid < 2048) ? x : qkv_w;
  bf16* dst = (bid < 2048) ? xb : qkv_wb;
  const int i = (((bid < 2048) ? bid : bid - 2048) * 256 + threadIdx.x) * 8;
  const floatx4 u = *(const floatx4*)(src + i);
  const floatx4 v = *(const floatx4*)(src + i + 4);
  bf16x8 r;
#pragma unroll
  for (int j = 0; j < 4; j++) { r[j] = (bf16)u[j]; r[4 + j] = (bf16)v[j]; }
  *(bf16x8*)(dst + i) = r;
}

// ======================================================================
// f32 -> bf16 bulk convert (out_w, after attn frees the Vt region)
// ======================================================================
__global__ __launch_bounds__(256) void cvt_f32_bf16(
    const float* __restrict__ src, bf16* __restrict__ dst, int n)
{
  const int i = (blockIdx.x * 256 + threadIdx.x) * 8;
  if (i >= n) return;
  const floatx4 u = *(const floatx4*)(src + i);
  const floatx4 v = *(const floatx4*)(src + i + 4);
  bf16x8 r;
#pragma unroll
  for (int j = 0; j < 4; j++) { r[j] = (bf16)u[j]; r[4 + j] = (bf16)v[j]; }
  *(bf16x8*)(dst + i) = r;
}

// ======================================================================
// gemm_qkv — 256x256 / BK=64 / 8 waves, 4-phase counted-vmcnt schedule
// (best-measured configuration, 43.0 us / ~600 TF):
//  - LDS 128 KiB: [2 dbuf][2 K-half] x [256][32] bf16 for A and B.
//  - per K-tile: 4 phases (kh,mh); each phase: ds_read + 2 glds16
//    + barrier + setprio(1) 16 MFMA setprio(0).
//  - counted vmcnt(4) ONLY at P1 (vouches tile-t kh1) and P3 (vouches
//    tile-t+1 kh0); never 0 mid-loop; tail iter drains vmcnt(0) at P1.
//  - zero-conflict XOR staging/read swizzle (SQ_LDS_BANK_CONFLICT = 0).
//  - grid 192, bijective 6x4 XCD chunking.
//  NOTE (r6-r10 ledger): B-persist reads, 2-barrier phases, BM=128
//  reshape (grid 384 = 1.5 serial rounds at 1 blk/CU) all null-to-worse;
//  kernel is schedule-insensitive at this shape.
//  Epilogue: fused RoPE (Q/K) + transposed V store (b,h,d,t).
// ======================================================================
__global__ __launch_bounds__(512, 2) void gemm_qkv(
    const bf16* __restrict__ A, const bf16* __restrict__ W,
    const float* __restrict__ bias, const float2* __restrict__ rope,
    bf16* __restrict__ Qb, bf16* __restrict__ Kb, bf16* __restrict__ Vt,
    int M, int N, int K)
{
  __shared__ bf16 As[2][2][256 * 32];
  __shared__ bf16 Bs[2][2][256 * 32];

  const int tid  = threadIdx.x;
  const int lane = tid & 63;
  const int wv   = tid >> 6;          // 0..7
  const int quad = lane >> 4;
  const int l16  = lane & 15;
  const int wm   = (wv >> 2) * 128;   // wave M-half (2 groups)
  const int wn   = (wv & 3) * 64;     // wave N-slot (4 groups) = one head

  // XCD-chunked swizzle: 8 rects of 6bx x 4by tiling the (12 x 16) grid
  const int f   = blockIdx.x;
  const int xcd = f & 7;
  const int rr  = f >> 3;                    // 0..23
  const int bx  = (xcd & 1) * 6 + rr % 6;    // 0..11
  const int by  = (xcd >> 1) * 4 + rr / 6;   // 0..15
  const int m0 = by * 256;
  const int n0 = bx * 256;

  const int srow = lane >> 2;                               // 0..15
  const int scol = ((lane & 3) ^ ((lane >> 3) & 3)) * 8;    // XOR-swz src granule
  const int qsw  = (quad ^ ((l16 >> 1) & 3)) * 8;           // matching read swz

  const bf16* gaBase = A + (size_t)(m0 + wv * 16 + srow) * K + scol;
  const bf16* gbBase = W + (size_t)(n0 + wv * 16 + srow) * K + scol;
  const int ldst = wv * 512 + lane * 8;   // LDS elems; volley 1 adds 4096

#define STG_A(d, kh, kcol)                                                   \
  glds16(&As[d][kh][ldst],        gaBase + (kcol));                          \
  glds16(&As[d][kh][ldst + 4096], gaBase + (size_t)128 * K + (kcol));
#define STG_B(d, kh, kcol)                                                   \
  glds16(&Bs[d][kh][ldst],        gbBase + (kcol));                          \
  glds16(&Bs[d][kh][ldst + 4096], gbBase + (size_t)128 * K + (kcol));

#define RD_PH(d, kh, mh)                                                     \
  _Pragma("unroll") for (int i = 0; i < 4; i++)                              \
    af[i] = *(const bf16x8*)(&As[d][kh][(wm + (mh) * 64 + i * 16 + l16) * 32 + qsw]); \
  _Pragma("unroll") for (int j = 0; j < 4; j++)                              \
    bfr[j] = *(const bf16x8*)(&Bs[d][kh][(wn + j * 16 + l16) * 32 + qsw]);

#define MM_PH(mh)                                                            \
  _Pragma("unroll") for (int i = 0; i < 4; i++)                              \
    _Pragma("unroll") for (int j = 0; j < 4; j++)                            \
      acc[(mh) * 4 + i][j] = __builtin_amdgcn_mfma_f32_16x16x32_bf16(        \
          af[i], bfr[j], acc[(mh) * 4 + i][j], 0, 0, 0);

  floatx4 acc[8][4];
#pragma unroll
  for (int i = 0; i < 8; i++)
#pragma unroll
    for (int j = 0; j < 4; j++) acc[i][j] = (floatx4){0.f, 0.f, 0.f, 0.f};

  // prologue: stage tile 0 (both K-halves) into buf 0
  STG_A(0, 0, 0); STG_B(0, 0, 0);
  STG_A(0, 1, 32); STG_B(0, 1, 32);
  asm volatile("s_waitcnt vmcnt(4)" ::: "memory");   // tile0 kh0 landed
  __builtin_amdgcn_s_barrier();

  const int nt = K >> 6;   // 16
#pragma unroll 1
  for (int t = 0; t < nt; t++) {
    const int c = t & 1;
    const int kn = (t + 1) * 64;
    const bool more = (t + 1 < nt);
    bf16x8 af[4], bfr[4];

    // ---- P0: (kh0, mh0); stage AK0(t+1) ----
    RD_PH(c, 0, 0);
    if (more) { STG_A(c ^ 1, 0, kn); }
    __builtin_amdgcn_s_barrier();
    __builtin_amdgcn_s_setprio(1); MM_PH(0); __builtin_amdgcn_s_setprio(0);

    // ---- P1: (kh0, mh1); stage BK0(t+1); vouch tile t kh1 ----
    RD_PH(c, 0, 1);
    if (more) {
      STG_B(c ^ 1, 0, kn);
      asm volatile("s_waitcnt vmcnt(4)" ::: "memory");
    } else {
      asm volatile("s_waitcnt vmcnt(0)" ::: "memory");
    }
    __builtin_amdgcn_s_barrier();
    __builtin_amdgcn_s_setprio(1); MM_PH(1); __builtin_amdgcn_s_setprio(0);

    // ---- P2: (kh1, mh0); stage AK1(t+1) ----
    RD_PH(c, 1, 0);
    if (more) { STG_A(c ^ 1, 1, kn + 32); }
    __builtin_amdgcn_s_barrier();
    __builtin_amdgcn_s_setprio(1); MM_PH(0); __builtin_amdgcn_s_setprio(0);

    // ---- P3: (kh1, mh1); stage BK1(t+1); vouch tile t+1 kh0 ----
    RD_PH(c, 1, 1);
    if (more) {
      STG_B(c ^ 1, 1, kn + 32);
      asm volatile("s_waitcnt vmcnt(4)" ::: "memory");
    }
    __builtin_amdgcn_s_barrier();
    __builtin_amdgcn_s_setprio(1); MM_PH(1); __builtin_amdgcn_s_setprio(0);
  }

  // ---- epilogue ----
  const int sect = n0 >> 10;                 // 0 = Q, 1 = K, 2 = V
  const int hw   = ((n0 & 1023) + wn) >> 6;  // head for this wave

  float bs[4];
#pragma unroll
  for (int j = 0; j < 4; j++) bs[j] = bias[n0 + wn + j * 16 + l16];

  if (sect < 2) {
    bf16* dst = sect ? Kb : Qb;
#pragma unroll
    for (int i = 0; i < 8; i++) {
      const int gmBase = m0 + wm + i * 16 + quad * 4;
#pragma unroll
      for (int r = 0; r < 4; r++) {
        const int gm = gmBase + r;
        const int b_ = gm >> 11, t = gm & 2047;
        const size_t rowbase = ((size_t)(b_ * NHEADS + hw) * TSEQ + t) * HDIM;
        const float2 cs0 = rope[t * 32 + l16];
        const float2 cs1 = rope[t * 32 + 16 + l16];
        const float x1a = acc[i][0][r] + bs[0];   // d = l16
        const float x2a = acc[i][2][r] + bs[2];   // d = l16 + 32
        const float x1b = acc[i][1][r] + bs[1];   // d = 16 + l16
        const float x2b = acc[i][3][r] + bs[3];   // d = 48 + l16
        dst[rowbase + l16]      = (bf16)(x1a * cs0.x - x2a * cs0.y);
        dst[rowbase + 32 + l16] = (bf16)(x1a * cs0.y + x2a * cs0.x);
        dst[rowbase + 16 + l16] = (bf16)(x1b * cs1.x - x2b * cs1.y);
        dst[rowbase + 48 + l16] = (bf16)(x1b * cs1.y + x2b * cs1.x);
      }
    }
  } else {
    // V: store transposed -> Vt[((b*16+h)*64 + d) * TSEQ + t], 8B packed over r
#pragma unroll
    for (int j = 0; j < 4; j++) {
      const int d = j * 16 + l16;
#pragma unroll
      for (int i = 0; i < 8; i++) {
        const int gmBase = m0 + wm + i * 16 + quad * 4;
        const int b_ = gmBase >> 11, t0 = gmBase & 2047;
        bf16x4 vv;
#pragma unroll
        for (int r = 0; r < 4; r++) vv[r] = (bf16)(acc[i][j][r] + bs[j]);
        *(bf16x4*)(Vt + ((size_t)((b_ * NHEADS + hw) * HDIM + d)) * TSEQ + t0) = vv;
      }
    }
  }
}

// ======================================================================
// gemm_out: 128x64 tile, grid 512 = 2 blocks/CU, triple-buffered LDS,
// counted vmcnt(3), XOR-swizzled staging, XCD-chunked swizzle (r4-proven).
// ======================================================================
__global__ __launch_bounds__(256) void gemm_out(
    const bf16* __restrict__ A, const bf16* __restrict__ W,
    const float* __restrict__ bias, float* __restrict__ C,
    int M, int N, int K)
{
  __shared__ bf16 As2[3][128 * 32];
  __shared__ bf16 Bs2[3][64 * 32];

  const int tid  = threadIdx.x;
  const int lane = tid & 63;
  const int wv   = tid >> 6;
  const int quad = lane >> 4;
  const int l16  = lane & 15;

  const int f   = blockIdx.x;
  const int xcd = f & 7;
  const int rr  = f >> 3;                    // 0..63
  const int bx  = (xcd & 1) * 8 + (rr & 7);
  const int by  = (xcd >> 1) * 8 + (rr >> 3);
  const int m0 = by * 128;
  const int n0 = bx * 64;
  const int wm = wv * 32;

  const int srow = lane >> 2;
  const int scol = ((lane & 3) ^ ((lane >> 3) & 3)) * 8;
  const int qsw  = (quad ^ ((l16 >> 1) & 3)) * 8;

  const bf16* ga0 = A + (size_t)(m0 + wv * 32 + srow) * K + scol;
  const bf16* gb0 = W + (size_t)(n0 + wv * 16 + srow) * K + scol;

  floatx4 acc[2][4];
#pragma unroll
  for (int i = 0; i < 2; i++)
#pragma unroll
    for (int j = 0; j < 4; j++) acc[i][j] = (floatx4){0.f, 0.f, 0.f, 0.f};

#define STAGE_O(buf, kk)                                                    \
  glds16(&As2[buf][(wv * 32) * 32], ga0 + (kk));                            \
  glds16(&As2[buf][(wv * 32 + 16) * 32], ga0 + (size_t)16 * K + (kk));      \
  glds16(&Bs2[buf][(wv * 16) * 32], gb0 + (kk));

#define COMPUTE_O(buf)                                                      \
  {                                                                         \
    bf16x8 af[2], bfr[4];                                                   \
    _Pragma("unroll") for (int i = 0; i < 2; i++)                           \
        af[i] = *(const bf16x8*)(&As2[buf][(wm + i * 16 + l16) * 32 + qsw]);\
    _Pragma("unroll") for (int j = 0; j < 4; j++)                           \
        bfr[j] = *(const bf16x8*)(&Bs2[buf][(j * 16 + l16) * 32 + qsw]);    \
    _Pragma("unroll") for (int i = 0; i < 2; i++)                           \
        _Pragma("unroll") for (int j = 0; j < 4; j++)                       \
            acc[i][j] = __builtin_amdgcn_mfma_f32_16x16x32_bf16(            \
                af[i], bfr[j], acc[i][j], 0, 0, 0);                         \
  }

  STAGE_O(0, 0);
  STAGE_O(1, 32);
  int cur = 0;
  const int nsteps = K / 32;
#pragma unroll 1
  for (int t = 0; t < nsteps - 1; t++) {
    asm volatile("s_waitcnt vmcnt(3)" ::: "memory");
    __builtin_amdgcn_s_barrier();
    if (t + 2 < nsteps) {
      const int nb = (cur >= 1) ? cur - 1 : cur + 2;
      STAGE_O(nb, (t + 2) * 32);
    }
    COMPUTE_O(cur);
    cur = (cur == 2) ? 0 : cur + 1;
  }
  asm volatile("s_waitcnt vmcnt(0)" ::: "memory");
  __builtin_amdgcn_s_barrier();
  COMPUTE_O(cur);

#pragma unroll
  for (int i = 0; i < 2; i++) {
    const int gmBase = m0 + wm + i * 16 + quad * 4;
#pragma unroll
    for (int j = 0; j < 4; j++) {
      const int gn = n0 + j * 16 + l16;
      const float bsv = bias[gn];
#pragma unroll
      for (int r = 0; r < 4; r++)
        C[(size_t)(gmBase + r) * N + gn] = acc[i][j][r] + bsv;
    }
  }
}

// ---- XOR granule swizzle for staging (reads lane-linear, conflict-free) ----
__device__ inline int swz(int g) { return (g & ~7) | ((g ^ (g >> 3) ^ (g >> 6)) & 7); }

// ======================================================================
// Flash attention v7 (best-measured): 512 blocks x 512 thr (8 waves).
// Key-split wave groups: waves 0-3 own keys [k0,k0+32), waves 4-7 own
// [k0+32,k0+64) of the same 64 q-rows.  Double-buffered K/V LDS, one
// barrier per 64-key chunk; cross-group O/lsum reduce via LDS scratch;
// balanced pairing {31-p, p} = 33 chunks/block; XCD-aware decode
// (4 bh/XCD -> L2-resident KV).  r7-r9 variants (128-key chunks, 1-qt
// blocks @ 2x occupancy) were null/regressed — not the gate.
// ======================================================================
__global__ __launch_bounds__(512) void attn_kernel(
    const bf16* __restrict__ Q, const bf16* __restrict__ K,
    const bf16* __restrict__ Vt, bf16* __restrict__ O,
    const int* __restrict__ ids, const int* __restrict__ gidx)
{
  __shared__ bf16 Ks[2][4096];
  __shared__ bf16 Vs[2][4096];
  __shared__ int flags[8];

  const int tid  = threadIdx.x;
  const int lane = tid & 63;
  const int wv   = tid >> 6;    // 0..7
  const int gg   = wv >> 2;     // key-half group
  const int w4   = wv & 3;      // row group (16 q-rows)
  const int quad = lane >> 4;
  const int l16  = lane & 15;

  const int xcd = blockIdx.x & 7;
  const int j   = blockIdx.x >> 3;
  const int bh  = xcd * 4 + (j >> 4);
  const int p   = j & 15;
  const int b  = bh >> 4;
  const int h  = bh & 15;

  const bf16* Qp = Q + (size_t)bh * TSEQ * HDIM;
  const bf16* Kp = K + (size_t)bh * TSEQ * HDIM;
  const bf16* Vp = Vt + (size_t)bh * HDIM * TSEQ;

  const int rK2 = tid >> 3, dcK = tid & 7;
  const int rKl = rK2 & 31, khi = rK2 >> 5;
  const int gk = ((rKl >> 2) & 1) * 128 + (dcK >> 2) * 64 +
                 ((dcK & 3) * 16 + (((rKl >> 3) << 2) | (rKl & 3)));
  const int kd = swz(gk + khi * 256) * 8;
  const int dV = tid >> 3, uV = tid & 7;
  const int gv = (uV >> 2) * 256 + (dV >> 4) * 64 + ((uV & 3) * 16 + (dV & 15));
  const int vd = swz(gv) * 8;

  const int g0v = gidx[0], g1v = gidx[1], g2v = gidx[2];

#pragma unroll
  for (int ph = 0; ph < 2; ph++) {
    const int qt = ph ? p : (31 - p);
    const int q0 = qt * 64 + w4 * 16;

    const bf16x8 qf0 = *(const bf16x8*)(Qp + (size_t)(q0 + l16) * HDIM + quad * 8);
    const bf16x8 qf1 = *(const bf16x8*)(Qp + (size_t)(q0 + l16) * HDIM + 32 + quad * 8);

    const int myq = q0 + l16;
    const int myid = ids[b * TSEQ + myq];
    const int gl = (myid == g0v) | (myid == g1v) | (myid == g2v);
    flags[wv] = __any(gl);
    __syncthreads();
    int anyg = 0;
#pragma unroll
    for (int i2 = 0; i2 < 8; i2++) anyg |= flags[i2];
    const int kmax = anyg ? TSEQ : (qt * 64 + 64);

    float lsum = 0.f;
    floatx4 o[4];
#pragma unroll
    for (int nt = 0; nt < 4; nt++) o[nt] = (floatx4){0.f, 0.f, 0.f, 0.f};

    bf16x8 kA = *(const bf16x8*)(Kp + tid * 8);
    bf16x8 vA = *(const bf16x8*)(Vp + (size_t)dV * TSEQ + uV * 8);

    for (int k0 = 0; k0 < kmax; k0 += 64) {
      bf16* KsB = Ks[(k0 >> 6) & 1];
      bf16* VsB = Vs[(k0 >> 6) & 1];
      *(bf16x8*)(KsB + kd) = kA;
      *(bf16x8*)(VsB + vd) = vA;
      __syncthreads();

      if (k0 + 64 < kmax) {
        kA = *(const bf16x8*)(Kp + (size_t)(k0 + 64) * HDIM + tid * 8);
        vA = *(const bf16x8*)(Vp + (size_t)dV * TSEQ + k0 + 64 + uV * 8);
      }

      const int kb = k0 + gg * 32;
      const int rb = gg * 256 + lane;
      const bf16x8 a00 = *(const bf16x8*)(KsB + swz(rb) * 8);
      const bf16x8 a01 = *(const bf16x8*)(KsB + swz(rb + 64) * 8);
      const bf16x8 a10 = *(const bf16x8*)(KsB + swz(rb + 128) * 8);
      const bf16x8 a11 = *(const bf16x8*)(KsB + swz(rb + 192) * 8);
      floatx4 s0 = (floatx4){0.f, 0.f, 0.f, 0.f};
      floatx4 s1 = (floatx4){0.f, 0.f, 0.f, 0.f};
      s0 = __builtin_amdgcn_mfma_f32_16x16x32_bf16(a00, qf0, s0, 0, 0, 0);
      s0 = __builtin_amdgcn_mfma_f32_16x16x32_bf16(a01, qf1, s0, 0, 0, 0);
      s1 = __builtin_amdgcn_mfma_f32_16x16x32_bf16(a10, qf0, s1, 0, 0, 0);
      s1 = __builtin_amdgcn_mfma_f32_16x16x32_bf16(a11, qf1, s1, 0, 0, 0);

      bf16x8 pf;
#pragma unroll
      for (int r = 0; r < 4; r++) {
        const int key0 = kb + quad * 8 + r;
        const int key1 = key0 + 4;
        const float p0 = (gl || key0 <= myq) ? __expf(s0[r] * 0.125f) : 0.f;
        const float p1 = (gl || key1 <= myq) ? __expf(s1[r] * 0.125f) : 0.f;
        lsum += p0 + p1;
        pf[r]     = (bf16)p0;
        pf[4 + r] = (bf16)p1;
      }

#pragma unroll
      for (int nt = 0; nt < 4; nt++) {
        const bf16x8 vf = *(const bf16x8*)(VsB + swz(gg * 256 + nt * 64 + lane) * 8);
        o[nt] = __builtin_amdgcn_mfma_f32_16x16x32_bf16(pf, vf, o[nt], 0, 0, 0);
      }
    }

    lsum += __shfl_xor(lsum, 16);
    lsum += __shfl_xor(lsum, 32);

    __syncthreads();
    float* osc = (float*)Ks;
    float* lsc = (float*)Vs;
    const int rbase = (w4 * 64 + lane) * 16;
    if (gg == 1) {
#pragma unroll
      for (int nt = 0; nt < 4; nt++)
        *(floatx4*)&osc[rbase + ((nt ^ (lane & 3)) * 4)] = o[nt];
      lsc[w4 * 64 + lane] = lsum;
    }
    __syncthreads();
    if (gg == 0) {
      lsum += lsc[w4 * 64 + lane];
#pragma unroll
      for (int nt = 0; nt < 4; nt++)
        o[nt] += *(const floatx4*)&osc[rbase + ((nt ^ (lane & 3)) * 4)];

#pragma unroll
      for (int r = 0; r < 4; r++) {
        const float inv = 1.0f / __shfl(lsum, quad * 4 + r);
        const int q = q0 + quad * 4 + r;
        const size_t rowoff = ((size_t)b * TSEQ + q) * HIDDEN + h * HDIM;
#pragma unroll
        for (int nt = 0; nt < 4; nt++)
          O[rowoff + nt * 16 + l16] = (bf16)(o[nt][r] * inv);
      }
    }
    __syncthreads();
  }
}

// ======================================================================
extern "C" void kernel_launch(void* const* d_in, const int* in_sizes, int n_in,
                              void* d_out, int out_size, void* d_ws, size_t ws_size,
                              hipStream_t stream)
{
  const float* x     = (const float*)d_in[0];
  const int*   ids   = (const int*)d_in[1];
  const float* qkv_w = (const float*)d_in[2];
  const float* qkv_b = (const float*)d_in[3];
  const float* out_w = (const float*)d_in[4];
  const float* out_b = (const float*)d_in[5];
  const int*   gidx  = (const int*)d_in[6];
  float* out = (float*)d_out;

  // ws (32 MiB): Q@0, K@8M, Vt@16M (written directly transposed by gemm_qkv),
  // slot24@24M multiplexed: xb (until gemm_qkv done) -> O (attn output).
  // out_wb (2 MiB) reuses Vt region after attn.  qkv_wb (6 MiB) lives in
  // d_out (dead until gemm_out overwrites it); rope table (512 KiB) lives at
  // d_out+6M (dead after gemm_qkv).
  char* ws = (char*)d_ws;
  bf16* Q      = (bf16*)(ws);
  bf16* Kb     = (bf16*)(ws + (size_t)(8u << 20));
  bf16* Vt     = (bf16*)(ws + (size_t)(16u << 20));
  bf16* slot24 = (bf16*)(ws + (size_t)(24u << 20));
  bf16* xb     = slot24;
  bf16* O      = slot24;
  bf16* out_wb = (bf16*)(ws + (size_t)(16u << 20));
  bf16* qkv_wb = (bf16*)d_out;
  float2* rope = (float2*)((char*)d_out + (size_t)(6u << 20));

  // 0) convert x + qkv_w, build rope cos/sin table
  prep_kernel<<<3648, 256, 0, stream>>>(x, xb, qkv_w, qkv_wb, rope);
  // 1) QKV projection -> Q/K (RoPE'd, (b,h,t,d)) + Vt ((b,h,d,t)) in one pass
  gemm_qkv<<<192, 512, 0, stream>>>(
      xb, qkv_wb, qkv_b, rope, Q, Kb, Vt, MTOT, 3 * HIDDEN, HIDDEN);
  // 2) attention -> O (b,t,hidden) in slot24 (xb dead)
  attn_kernel<<<512, 512, 0, stream>>>(Q, Kb, Vt, O, ids, gidx);
  // 3) convert out_w (overwrites Vt, dead)
  cvt_f32_bf16<<<512, 256, 0, stream>>>(out_w, out_wb, HIDDEN * HIDDEN);
  // 4) output projection -> d_out (overwrites qkv_wb + rope, dead)
  gemm_out<<<512, 256, 0, stream>>>(
      O, out_wb, out_b, out, MTOT, HIDDEN, HIDDEN);
}

// Round 12
// 178.290 us; speedup vs baseline: 1.0883x; 1.0205x over previous
//
#include <hip/hip_runtime.h>
#include <hip/hip_bf16.h>
#include <math.h>

typedef __bf16 bf16;
typedef __bf16 bf16x4 __attribute__((ext_vector_type(4)));
typedef __bf16 bf16x8 __attribute__((ext_vector_type(8)));
typedef float floatx4 __attribute__((ext_vector_type(4)));

#define HIDDEN 1024
#define NHEADS 16
#define HDIM 64
#define TSEQ 2048
#define NBATCH 2
#define MTOT (NBATCH * TSEQ) /* 4096 */

// ---- async 16B global->LDS. lds addr must be wave-uniform base + lane*16. ----
__device__ inline void glds16(bf16* lds, const bf16* g)
{
  __builtin_amdgcn_global_load_lds(
      (const __attribute__((address_space(1))) unsigned int*)g,
      (__attribute__((address_space(3))) unsigned int*)lds, 16, 0, 0);
}

// ======================================================================
// prep: cvt x (blocks 0..2047) + cvt qkv_w (blocks 2048..3583)
//       + rope cos/sin table [TSEQ][32] float2 (blocks 3584..3647)
// ======================================================================
__global__ __launch_bounds__(256) void prep_kernel(
    const float* __restrict__ x, bf16* __restrict__ xb,
    const float* __restrict__ qkv_w, bf16* __restrict__ qkv_wb,
    float2* __restrict__ rope)
{
  const int bid = blockIdx.x;
  if (bid >= 3584) {
    const int e0 = ((bid - 3584) * 256 + threadIdx.x) * 4;
    const int t = e0 >> 5;
    const int d2 = e0 & 31;
#pragma unroll
    for (int j = 0; j < 4; j++) {
      const float inv = exp2f((float)(d2 + j) * -0.41524100f);
      float s, c;
      sincosf((float)t * inv, &s, &c);
      rope[e0 + j] = make_float2(c, s);
    }
    return;
  }
  const float* src = (bid < 2048) ? x : qkv_w;
  bf16* dst = (bid < 2048) ? xb : qkv_wb;
  const int i = (((bid < 2048) ? bid : bid - 2048) * 256 + threadIdx.x) * 8;
  const floatx4 u = *(const floatx4*)(src + i);
  const floatx4 v = *(const floatx4*)(src + i + 4);
  bf16x8 r;
#pragma unroll
  for (int j = 0; j < 4; j++) { r[j] = (bf16)u[j]; r[4 + j] = (bf16)v[j]; }
  *(bf16x8*)(dst + i) = r;
}

// ======================================================================
// f32 -> bf16 bulk convert (out_w, after attn frees the Vt region)
// ======================================================================
__global__ __launch_bounds__(256) void cvt_f32_bf16(
    const float* __restrict__ src, bf16* __restrict__ dst, int n)
{
  const int i = (blockIdx.x * 256 + threadIdx.x) * 8;
  if (i >= n) return;
  const floatx4 u = *(const floatx4*)(src + i);
  const floatx4 v = *(const floatx4*)(src + i + 4);
  bf16x8 r;
#pragma unroll
  for (int j = 0; j < 4; j++) { r[j] = (bf16)u[j]; r[4 + j] = (bf16)v[j]; }
  *(bf16x8*)(dst + i) = r;
}

// ======================================================================
// gemm_qkv — 256x256 / BK=64 / 8 waves, 4-phase counted-vmcnt schedule
// (best-measured, 43.0 us).  r12 change: Q outputs pre-scaled by 0.125
// (exact power-of-2 in bf16; commutes with all f32 rounding) so attn's
// softmax drops its per-element scale mul.  Everything else frozen.
// ======================================================================
__global__ __launch_bounds__(512, 2) void gemm_qkv(
    const bf16* __restrict__ A, const bf16* __restrict__ W,
    const float* __restrict__ bias, const float2* __restrict__ rope,
    bf16* __restrict__ Qb, bf16* __restrict__ Kb, bf16* __restrict__ Vt,
    int M, int N, int K)
{
  __shared__ bf16 As[2][2][256 * 32];
  __shared__ bf16 Bs[2][2][256 * 32];

  const int tid  = threadIdx.x;
  const int lane = tid & 63;
  const int wv   = tid >> 6;          // 0..7
  const int quad = lane >> 4;
  const int l16  = lane & 15;
  const int wm   = (wv >> 2) * 128;   // wave M-half (2 groups)
  const int wn   = (wv & 3) * 64;     // wave N-slot (4 groups) = one head

  // XCD-chunked swizzle: 8 rects of 6bx x 4by tiling the (12 x 16) grid
  const int f   = blockIdx.x;
  const int xcd = f & 7;
  const int rr  = f >> 3;                    // 0..23
  const int bx  = (xcd & 1) * 6 + rr % 6;    // 0..11
  const int by  = (xcd >> 1) * 4 + rr / 6;   // 0..15
  const int m0 = by * 256;
  const int n0 = bx * 256;

  const int srow = lane >> 2;                               // 0..15
  const int scol = ((lane & 3) ^ ((lane >> 3) & 3)) * 8;    // XOR-swz src granule
  const int qsw  = (quad ^ ((l16 >> 1) & 3)) * 8;           // matching read swz

  const bf16* gaBase = A + (size_t)(m0 + wv * 16 + srow) * K + scol;
  const bf16* gbBase = W + (size_t)(n0 + wv * 16 + srow) * K + scol;
  const int ldst = wv * 512 + lane * 8;   // LDS elems; volley 1 adds 4096

#define STG_A(d, kh, kcol)                                                   \
  glds16(&As[d][kh][ldst],        gaBase + (kcol));                          \
  glds16(&As[d][kh][ldst + 4096], gaBase + (size_t)128 * K + (kcol));
#define STG_B(d, kh, kcol)                                                   \
  glds16(&Bs[d][kh][ldst],        gbBase + (kcol));                          \
  glds16(&Bs[d][kh][ldst + 4096], gbBase + (size_t)128 * K + (kcol));

#define RD_PH(d, kh, mh)                                                     \
  _Pragma("unroll") for (int i = 0; i < 4; i++)                              \
    af[i] = *(const bf16x8*)(&As[d][kh][(wm + (mh) * 64 + i * 16 + l16) * 32 + qsw]); \
  _Pragma("unroll") for (int j = 0; j < 4; j++)                              \
    bfr[j] = *(const bf16x8*)(&Bs[d][kh][(wn + j * 16 + l16) * 32 + qsw]);

#define MM_PH(mh)                                                            \
  _Pragma("unroll") for (int i = 0; i < 4; i++)                              \
    _Pragma("unroll") for (int j = 0; j < 4; j++)                            \
      acc[(mh) * 4 + i][j] = __builtin_amdgcn_mfma_f32_16x16x32_bf16(        \
          af[i], bfr[j], acc[(mh) * 4 + i][j], 0, 0, 0);

  floatx4 acc[8][4];
#pragma unroll
  for (int i = 0; i < 8; i++)
#pragma unroll
    for (int j = 0; j < 4; j++) acc[i][j] = (floatx4){0.f, 0.f, 0.f, 0.f};

  // prologue: stage tile 0 (both K-halves) into buf 0
  STG_A(0, 0, 0); STG_B(0, 0, 0);
  STG_A(0, 1, 32); STG_B(0, 1, 32);
  asm volatile("s_waitcnt vmcnt(4)" ::: "memory");   // tile0 kh0 landed
  __builtin_amdgcn_s_barrier();

  const int nt = K >> 6;   // 16
#pragma unroll 1
  for (int t = 0; t < nt; t++) {
    const int c = t & 1;
    const int kn = (t + 1) * 64;
    const bool more = (t + 1 < nt);
    bf16x8 af[4], bfr[4];

    // ---- P0: (kh0, mh0); stage AK0(t+1) ----
    RD_PH(c, 0, 0);
    if (more) { STG_A(c ^ 1, 0, kn); }
    __builtin_amdgcn_s_barrier();
    __builtin_amdgcn_s_setprio(1); MM_PH(0); __builtin_amdgcn_s_setprio(0);

    // ---- P1: (kh0, mh1); stage BK0(t+1); vouch tile t kh1 ----
    RD_PH(c, 0, 1);
    if (more) {
      STG_B(c ^ 1, 0, kn);
      asm volatile("s_waitcnt vmcnt(4)" ::: "memory");
    } else {
      asm volatile("s_waitcnt vmcnt(0)" ::: "memory");
    }
    __builtin_amdgcn_s_barrier();
    __builtin_amdgcn_s_setprio(1); MM_PH(1); __builtin_amdgcn_s_setprio(0);

    // ---- P2: (kh1, mh0); stage AK1(t+1) ----
    RD_PH(c, 1, 0);
    if (more) { STG_A(c ^ 1, 1, kn + 32); }
    __builtin_amdgcn_s_barrier();
    __builtin_amdgcn_s_setprio(1); MM_PH(0); __builtin_amdgcn_s_setprio(0);

    // ---- P3: (kh1, mh1); stage BK1(t+1); vouch tile t+1 kh0 ----
    RD_PH(c, 1, 1);
    if (more) {
      STG_B(c ^ 1, 1, kn + 32);
      asm volatile("s_waitcnt vmcnt(4)" ::: "memory");
    }
    __builtin_amdgcn_s_barrier();
    __builtin_amdgcn_s_setprio(1); MM_PH(1); __builtin_amdgcn_s_setprio(0);
  }

  // ---- epilogue ----
  const int sect = n0 >> 10;                 // 0 = Q, 1 = K, 2 = V
  const int hw   = ((n0 & 1023) + wn) >> 6;  // head for this wave

  float bs[4];
#pragma unroll
  for (int j = 0; j < 4; j++) bs[j] = bias[n0 + wn + j * 16 + l16];

  if (sect < 2) {
    bf16* dst = sect ? Kb : Qb;
    const float qs = sect ? 1.0f : 0.125f;   // fold softmax 1/sqrt(64) into Q (exact 2^-3)
#pragma unroll
    for (int i = 0; i < 8; i++) {
      const int gmBase = m0 + wm + i * 16 + quad * 4;
#pragma unroll
      for (int r = 0; r < 4; r++) {
        const int gm = gmBase + r;
        const int b_ = gm >> 11, t = gm & 2047;
        const size_t rowbase = ((size_t)(b_ * NHEADS + hw) * TSEQ + t) * HDIM;
        const float2 cs0 = rope[t * 32 + l16];
        const float2 cs1 = rope[t * 32 + 16 + l16];
        const float x1a = acc[i][0][r] + bs[0];   // d = l16
        const float x2a = acc[i][2][r] + bs[2];   // d = l16 + 32
        const float x1b = acc[i][1][r] + bs[1];   // d = 16 + l16
        const float x2b = acc[i][3][r] + bs[3];   // d = 48 + l16
        dst[rowbase + l16]      = (bf16)((x1a * cs0.x - x2a * cs0.y) * qs);
        dst[rowbase + 32 + l16] = (bf16)((x1a * cs0.y + x2a * cs0.x) * qs);
        dst[rowbase + 16 + l16] = (bf16)((x1b * cs1.x - x2b * cs1.y) * qs);
        dst[rowbase + 48 + l16] = (bf16)((x1b * cs1.y + x2b * cs1.x) * qs);
      }
    }
  } else {
    // V: store transposed -> Vt[((b*16+h)*64 + d) * TSEQ + t], 8B packed over r
#pragma unroll
    for (int j = 0; j < 4; j++) {
      const int d = j * 16 + l16;
#pragma unroll
      for (int i = 0; i < 8; i++) {
        const int gmBase = m0 + wm + i * 16 + quad * 4;
        const int b_ = gmBase >> 11, t0 = gmBase & 2047;
        bf16x4 vv;
#pragma unroll
        for (int r = 0; r < 4; r++) vv[r] = (bf16)(acc[i][j][r] + bs[j]);
        *(bf16x4*)(Vt + ((size_t)((b_ * NHEADS + hw) * HDIM + d)) * TSEQ + t0) = vv;
      }
    }
  }
}

// ======================================================================
// gemm_out: 128x64 tile, grid 512 = 2 blocks/CU, triple-buffered LDS,
// counted vmcnt(3), XOR-swizzled staging, XCD-chunked swizzle (r4-proven).
// ======================================================================
__global__ __launch_bounds__(256) void gemm_out(
    const bf16* __restrict__ A, const bf16* __restrict__ W,
    const float* __restrict__ bias, float* __restrict__ C,
    int M, int N, int K)
{
  __shared__ bf16 As2[3][128 * 32];
  __shared__ bf16 Bs2[3][64 * 32];

  const int tid  = threadIdx.x;
  const int lane = tid & 63;
  const int wv   = tid >> 6;
  const int quad = lane >> 4;
  const int l16  = lane & 15;

  const int f   = blockIdx.x;
  const int xcd = f & 7;
  const int rr  = f >> 3;                    // 0..63
  const int bx  = (xcd & 1) * 8 + (rr & 7);
  const int by  = (xcd >> 1) * 8 + (rr >> 3);
  const int m0 = by * 128;
  const int n0 = bx * 64;
  const int wm = wv * 32;

  const int srow = lane >> 2;
  const int scol = ((lane & 3) ^ ((lane >> 3) & 3)) * 8;
  const int qsw  = (quad ^ ((l16 >> 1) & 3)) * 8;

  const bf16* ga0 = A + (size_t)(m0 + wv * 32 + srow) * K + scol;
  const bf16* gb0 = W + (size_t)(n0 + wv * 16 + srow) * K + scol;

  floatx4 acc[2][4];
#pragma unroll
  for (int i = 0; i < 2; i++)
#pragma unroll
    for (int j = 0; j < 4; j++) acc[i][j] = (floatx4){0.f, 0.f, 0.f, 0.f};

#define STAGE_O(buf, kk)                                                    \
  glds16(&As2[buf][(wv * 32) * 32], ga0 + (kk));                            \
  glds16(&As2[buf][(wv * 32 + 16) * 32], ga0 + (size_t)16 * K + (kk));      \
  glds16(&Bs2[buf][(wv * 16) * 32], gb0 + (kk));

#define COMPUTE_O(buf)                                                      \
  {                                                                         \
    bf16x8 af[2], bfr[4];                                                   \
    _Pragma("unroll") for (int i = 0; i < 2; i++)                           \
        af[i] = *(const bf16x8*)(&As2[buf][(wm + i * 16 + l16) * 32 + qsw]);\
    _Pragma("unroll") for (int j = 0; j < 4; j++)                           \
        bfr[j] = *(const bf16x8*)(&Bs2[buf][(j * 16 + l16) * 32 + qsw]);    \
    _Pragma("unroll") for (int i = 0; i < 2; i++)                           \
        _Pragma("unroll") for (int j = 0; j < 4; j++)                       \
            acc[i][j] = __builtin_amdgcn_mfma_f32_16x16x32_bf16(            \
                af[i], bfr[j], acc[i][j], 0, 0, 0);                         \
  }

  STAGE_O(0, 0);
  STAGE_O(1, 32);
  int cur = 0;
  const int nsteps = K / 32;
#pragma unroll 1
  for (int t = 0; t < nsteps - 1; t++) {
    asm volatile("s_waitcnt vmcnt(3)" ::: "memory");
    __builtin_amdgcn_s_barrier();
    if (t + 2 < nsteps) {
      const int nb = (cur >= 1) ? cur - 1 : cur + 2;
      STAGE_O(nb, (t + 2) * 32);
    }
    COMPUTE_O(cur);
    cur = (cur == 2) ? 0 : cur + 1;
  }
  asm volatile("s_waitcnt vmcnt(0)" ::: "memory");
  __builtin_amdgcn_s_barrier();
  COMPUTE_O(cur);

#pragma unroll
  for (int i = 0; i < 2; i++) {
    const int gmBase = m0 + wm + i * 16 + quad * 4;
#pragma unroll
    for (int j = 0; j < 4; j++) {
      const int gn = n0 + j * 16 + l16;
      const float bsv = bias[gn];
#pragma unroll
      for (int r = 0; r < 4; r++)
        C[(size_t)(gmBase + r) * N + gn] = acc[i][j][r] + bsv;
    }
  }
}

// ---- XOR granule swizzle for staging (reads lane-linear, conflict-free) ----
__device__ inline int swz(int g) { return (g & ~7) | ((g ^ (g >> 3) ^ (g >> 6)) & 7); }

// ======================================================================
// Flash attention v10 = v7 + VALU diet (r11 counters: VALUBusy 51.4%,
// MfmaUtil 16.7% -> inner loop is VALU-bound, ~3:1 over MFMA).
//  - causal masking split by UNIFORM chunk class: chunks k0 < qt*64 are
//    provably unmasked for every lane (key <= kfull-1 < myq); only the
//    diagonal chunk k0 == qt*64 needs key<=myq; chunks beyond (anyg
//    only) reduce to (gl ? exp : 0).  s_cbranch on uniform scalars, no
//    divergence; kills 16 compare/select VALU ops in 31 of 33 chunks.
//  - softmax scale dropped: Q is pre-scaled by 0.125 in gemm_qkv
//    (exact; exp inputs bitwise identical).
// Structure otherwise identical to v7 (best-measured).
// ======================================================================
__global__ __launch_bounds__(512) void attn_kernel(
    const bf16* __restrict__ Q, const bf16* __restrict__ K,
    const bf16* __restrict__ Vt, bf16* __restrict__ O,
    const int* __restrict__ ids, const int* __restrict__ gidx)
{
  __shared__ bf16 Ks[2][4096];
  __shared__ bf16 Vs[2][4096];
  __shared__ int flags[8];

  const int tid  = threadIdx.x;
  const int lane = tid & 63;
  const int wv   = tid >> 6;    // 0..7
  const int gg   = wv >> 2;     // key-half group
  const int w4   = wv & 3;      // row group (16 q-rows)
  const int quad = lane >> 4;
  const int l16  = lane & 15;

  const int xcd = blockIdx.x & 7;
  const int j   = blockIdx.x >> 3;
  const int bh  = xcd * 4 + (j >> 4);
  const int p   = j & 15;
  const int b  = bh >> 4;
  const int h  = bh & 15;

  const bf16* Qp = Q + (size_t)bh * TSEQ * HDIM;
  const bf16* Kp = K + (size_t)bh * TSEQ * HDIM;
  const bf16* Vp = Vt + (size_t)bh * HDIM * TSEQ;

  const int rK2 = tid >> 3, dcK = tid & 7;
  const int rKl = rK2 & 31, khi = rK2 >> 5;
  const int gk = ((rKl >> 2) & 1) * 128 + (dcK >> 2) * 64 +
                 ((dcK & 3) * 16 + (((rKl >> 3) << 2) | (rKl & 3)));
  const int kd = swz(gk + khi * 256) * 8;
  const int dV = tid >> 3, uV = tid & 7;
  const int gv = (uV >> 2) * 256 + (dV >> 4) * 64 + ((uV & 3) * 16 + (dV & 15));
  const int vd = swz(gv) * 8;

  const int g0v = gidx[0], g1v = gidx[1], g2v = gidx[2];

#pragma unroll
  for (int ph = 0; ph < 2; ph++) {
    const int qt = ph ? p : (31 - p);
    const int q0 = qt * 64 + w4 * 16;
    const int kfull = qt * 64;   // chunks strictly below: unmasked for all lanes

    const bf16x8 qf0 = *(const bf16x8*)(Qp + (size_t)(q0 + l16) * HDIM + quad * 8);
    const bf16x8 qf1 = *(const bf16x8*)(Qp + (size_t)(q0 + l16) * HDIM + 32 + quad * 8);

    const int myq = q0 + l16;
    const int myid = ids[b * TSEQ + myq];
    const int gl = (myid == g0v) | (myid == g1v) | (myid == g2v);
    flags[wv] = __any(gl);
    __syncthreads();
    int anyg = 0;
#pragma unroll
    for (int i2 = 0; i2 < 8; i2++) anyg |= flags[i2];
    const int kmax = anyg ? TSEQ : (qt * 64 + 64);

    float lsum = 0.f;
    floatx4 o[4];
#pragma unroll
    for (int nt = 0; nt < 4; nt++) o[nt] = (floatx4){0.f, 0.f, 0.f, 0.f};

    bf16x8 kA = *(const bf16x8*)(Kp + tid * 8);
    bf16x8 vA = *(const bf16x8*)(Vp + (size_t)dV * TSEQ + uV * 8);

    for (int k0 = 0; k0 < kmax; k0 += 64) {
      bf16* KsB = Ks[(k0 >> 6) & 1];
      bf16* VsB = Vs[(k0 >> 6) & 1];
      *(bf16x8*)(KsB + kd) = kA;
      *(bf16x8*)(VsB + vd) = vA;
      __syncthreads();

      if (k0 + 64 < kmax) {
        kA = *(const bf16x8*)(Kp + (size_t)(k0 + 64) * HDIM + tid * 8);
        vA = *(const bf16x8*)(Vp + (size_t)dV * TSEQ + k0 + 64 + uV * 8);
      }

      const int kb = k0 + gg * 32;
      const int rb = gg * 256 + lane;
      const bf16x8 a00 = *(const bf16x8*)(KsB + swz(rb) * 8);
      const bf16x8 a01 = *(const bf16x8*)(KsB + swz(rb + 64) * 8);
      const bf16x8 a10 = *(const bf16x8*)(KsB + swz(rb + 128) * 8);
      const bf16x8 a11 = *(const bf16x8*)(KsB + swz(rb + 192) * 8);
      floatx4 s0 = (floatx4){0.f, 0.f, 0.f, 0.f};
      floatx4 s1 = (floatx4){0.f, 0.f, 0.f, 0.f};
      s0 = __builtin_amdgcn_mfma_f32_16x16x32_bf16(a00, qf0, s0, 0, 0, 0);
      s0 = __builtin_amdgcn_mfma_f32_16x16x32_bf16(a01, qf1, s0, 0, 0, 0);
      s1 = __builtin_amdgcn_mfma_f32_16x16x32_bf16(a10, qf0, s1, 0, 0, 0);
      s1 = __builtin_amdgcn_mfma_f32_16x16x32_bf16(a11, qf1, s1, 0, 0, 0);

      bf16x8 pf;
      if (k0 < kfull) {
        // fully unmasked chunk (uniform branch): p = exp(s), no compares
#pragma unroll
        for (int r = 0; r < 4; r++) {
          const float p0 = __expf(s0[r]);
          const float p1 = __expf(s1[r]);
          lsum += p0 + p1;
          pf[r]     = (bf16)p0;
          pf[4 + r] = (bf16)p1;
        }
      } else if (k0 == kfull) {
        // diagonal chunk: causal mask needed
#pragma unroll
        for (int r = 0; r < 4; r++) {
          const int key0 = kb + quad * 8 + r;
          const int key1 = key0 + 4;
          const float p0 = (gl || key0 <= myq) ? __expf(s0[r]) : 0.f;
          const float p1 = (gl || key1 <= myq) ? __expf(s1[r]) : 0.f;
          lsum += p0 + p1;
          pf[r]     = (bf16)p0;
          pf[4 + r] = (bf16)p1;
        }
      } else {
        // beyond-diagonal (anyg rows only): key > myq always -> gl gate only
#pragma unroll
        for (int r = 0; r < 4; r++) {
          const float p0 = gl ? __expf(s0[r]) : 0.f;
          const float p1 = gl ? __expf(s1[r]) : 0.f;
          lsum += p0 + p1;
          pf[r]     = (bf16)p0;
          pf[4 + r] = (bf16)p1;
        }
      }

#pragma unroll
      for (int nt = 0; nt < 4; nt++) {
        const bf16x8 vf = *(const bf16x8*)(VsB + swz(gg * 256 + nt * 64 + lane) * 8);
        o[nt] = __builtin_amdgcn_mfma_f32_16x16x32_bf16(pf, vf, o[nt], 0, 0, 0);
      }
    }

    lsum += __shfl_xor(lsum, 16);
    lsum += __shfl_xor(lsum, 32);

    __syncthreads();
    float* osc = (float*)Ks;
    float* lsc = (float*)Vs;
    const int rbase = (w4 * 64 + lane) * 16;
    if (gg == 1) {
#pragma unroll
      for (int nt = 0; nt < 4; nt++)
        *(floatx4*)&osc[rbase + ((nt ^ (lane & 3)) * 4)] = o[nt];
      lsc[w4 * 64 + lane] = lsum;
    }
    __syncthreads();
    if (gg == 0) {
      lsum += lsc[w4 * 64 + lane];
#pragma unroll
      for (int nt = 0; nt < 4; nt++)
        o[nt] += *(const floatx4*)&osc[rbase + ((nt ^ (lane & 3)) * 4)];

#pragma unroll
      for (int r = 0; r < 4; r++) {
        const float inv = 1.0f / __shfl(lsum, quad * 4 + r);
        const int q = q0 + quad * 4 + r;
        const size_t rowoff = ((size_t)b * TSEQ + q) * HIDDEN + h * HDIM;
#pragma unroll
        for (int nt = 0; nt < 4; nt++)
          O[rowoff + nt * 16 + l16] = (bf16)(o[nt][r] * inv);
      }
    }
    __syncthreads();
  }
}

// ======================================================================
extern "C" void kernel_launch(void* const* d_in, const int* in_sizes, int n_in,
                              void* d_out, int out_size, void* d_ws, size_t ws_size,
                              hipStream_t stream)
{
  const float* x     = (const float*)d_in[0];
  const int*   ids   = (const int*)d_in[1];
  const float* qkv_w = (const float*)d_in[2];
  const float* qkv_b = (const float*)d_in[3];
  const float* out_w = (const float*)d_in[4];
  const float* out_b = (const float*)d_in[5];
  const int*   gidx  = (const int*)d_in[6];
  float* out = (float*)d_out;

  // ws (32 MiB): Q@0, K@8M, Vt@16M (written directly transposed by gemm_qkv),
  // slot24@24M multiplexed: xb (until gemm_qkv done) -> O (attn output).
  // out_wb (2 MiB) reuses Vt region after attn.  qkv_wb (6 MiB) lives in
  // d_out (dead until gemm_out overwrites it); rope table (512 KiB) lives at
  // d_out+6M (dead after gemm_qkv).
  char* ws = (char*)d_ws;
  bf16* Q      = (bf16*)(ws);
  bf16* Kb     = (bf16*)(ws + (size_t)(8u << 20));
  bf16* Vt     = (bf16*)(ws + (size_t)(16u << 20));
  bf16* slot24 = (bf16*)(ws + (size_t)(24u << 20));
  bf16* xb     = slot24;
  bf16* O      = slot24;
  bf16* out_wb = (bf16*)(ws + (size_t)(16u << 20));
  bf16* qkv_wb = (bf16*)d_out;
  float2* rope = (float2*)((char*)d_out + (size_t)(6u << 20));

  // 0) convert x + qkv_w, build rope cos/sin table
  prep_kernel<<<3648, 256, 0, stream>>>(x, xb, qkv_w, qkv_wb, rope);
  // 1) QKV projection -> Q (RoPE'd + 0.125-scaled) / K (RoPE'd) + Vt
  gemm_qkv<<<192, 512, 0, stream>>>(
      xb, qkv_wb, qkv_b, rope, Q, Kb, Vt, MTOT, 3 * HIDDEN, HIDDEN);
  // 2) attention -> O (b,t,hidden) in slot24 (xb dead)
  attn_kernel<<<512, 512, 0, stream>>>(Q, Kb, Vt, O, ids, gidx);
  // 3) convert out_w (overwrites Vt, dead)
  cvt_f32_bf16<<<512, 256, 0, stream>>>(out_w, out_wb, HIDDEN * HIDDEN);
  // 4) output projection -> d_out (overwrites qkv_wb + rope, dead)
  gemm_out<<<512, 256, 0, stream>>>(
      O, out_wb, out_b, out, MTOT, HIDDEN, HIDDEN);
}

// Round 13
// 174.762 us; speedup vs baseline: 1.1103x; 1.0202x over previous
//
#include <hip/hip_runtime.h>
#include <hip/hip_bf16.h>
#include <math.h>

typedef __bf16 bf16;
typedef __bf16 bf16x4 __attribute__((ext_vector_type(4)));
typedef __bf16 bf16x8 __attribute__((ext_vector_type(8)));
typedef float floatx4 __attribute__((ext_vector_type(4)));

#define HIDDEN 1024
#define NHEADS 16
#define HDIM 64
#define TSEQ 2048
#define NBATCH 2
#define MTOT (NBATCH * TSEQ) /* 4096 */

// ---- async 16B global->LDS. lds addr must be wave-uniform base + lane*16. ----
__device__ inline void glds16(bf16* lds, const bf16* g)
{
  __builtin_amdgcn_global_load_lds(
      (const __attribute__((address_space(1))) unsigned int*)g,
      (__attribute__((address_space(3))) unsigned int*)lds, 16, 0, 0);
}

// ======================================================================
// prep: cvt x (blocks 0..2047) + cvt qkv_w (blocks 2048..3583)
//       + rope cos/sin table [TSEQ][32] float2 (blocks 3584..3647)
//       + cvt out_w (blocks 3648..4159, only when launched with 4160:
//         fused from the old cvt_f32_bf16 kernel; dst = ws+32M, safe
//         for the whole pipeline when ws_size >= 34 MiB)
// ======================================================================
__global__ __launch_bounds__(256) void prep_kernel(
    const float* __restrict__ x, bf16* __restrict__ xb,
    const float* __restrict__ qkv_w, bf16* __restrict__ qkv_wb,
    float2* __restrict__ rope,
    const float* __restrict__ out_w, bf16* __restrict__ out_wb)
{
  const int bid = blockIdx.x;
  if (bid >= 3648) {
    const int i = ((bid - 3648) * 256 + threadIdx.x) * 8;
    const floatx4 u = *(const floatx4*)(out_w + i);
    const floatx4 v = *(const floatx4*)(out_w + i + 4);
    bf16x8 r;
#pragma unroll
    for (int j = 0; j < 4; j++) { r[j] = (bf16)u[j]; r[4 + j] = (bf16)v[j]; }
    *(bf16x8*)(out_wb + i) = r;
    return;
  }
  if (bid >= 3584) {
    const int e0 = ((bid - 3584) * 256 + threadIdx.x) * 4;
    const int t = e0 >> 5;
    const int d2 = e0 & 31;
#pragma unroll
    for (int j = 0; j < 4; j++) {
      const float inv = exp2f((float)(d2 + j) * -0.41524100f);
      float s, c;
      sincosf((float)t * inv, &s, &c);
      rope[e0 + j] = make_float2(c, s);
    }
    return;
  }
  const float* src = (bid < 2048) ? x : qkv_w;
  bf16* dst = (bid < 2048) ? xb : qkv_wb;
  const int i = (((bid < 2048) ? bid : bid - 2048) * 256 + threadIdx.x) * 8;
  const floatx4 u = *(const floatx4*)(src + i);
  const floatx4 v = *(const floatx4*)(src + i + 4);
  bf16x8 r;
#pragma unroll
  for (int j = 0; j < 4; j++) { r[j] = (bf16)u[j]; r[4 + j] = (bf16)v[j]; }
  *(bf16x8*)(dst + i) = r;
}

// ======================================================================
// f32 -> bf16 bulk convert (fallback only, when ws_size < 34 MiB)
// ======================================================================
__global__ __launch_bounds__(256) void cvt_f32_bf16(
    const float* __restrict__ src, bf16* __restrict__ dst, int n)
{
  const int i = (blockIdx.x * 256 + threadIdx.x) * 8;
  if (i >= n) return;
  const floatx4 u = *(const floatx4*)(src + i);
  const floatx4 v = *(const floatx4*)(src + i + 4);
  bf16x8 r;
#pragma unroll
  for (int j = 0; j < 4; j++) { r[j] = (bf16)u[j]; r[4 + j] = (bf16)v[j]; }
  *(bf16x8*)(dst + i) = r;
}

// ======================================================================
// gemm_qkv — 256x256 / BK=64 / 8 waves, 4-phase counted-vmcnt schedule
// (best-measured, ~42 us).  Q outputs pre-scaled by 0.125 (exact).
// ======================================================================
__global__ __launch_bounds__(512, 2) void gemm_qkv(
    const bf16* __restrict__ A, const bf16* __restrict__ W,
    const float* __restrict__ bias, const float2* __restrict__ rope,
    bf16* __restrict__ Qb, bf16* __restrict__ Kb, bf16* __restrict__ Vt,
    int M, int N, int K)
{
  __shared__ bf16 As[2][2][256 * 32];
  __shared__ bf16 Bs[2][2][256 * 32];

  const int tid  = threadIdx.x;
  const int lane = tid & 63;
  const int wv   = tid >> 6;          // 0..7
  const int quad = lane >> 4;
  const int l16  = lane & 15;
  const int wm   = (wv >> 2) * 128;   // wave M-half (2 groups)
  const int wn   = (wv & 3) * 64;     // wave N-slot (4 groups) = one head

  // XCD-chunked swizzle: 8 rects of 6bx x 4by tiling the (12 x 16) grid
  const int f   = blockIdx.x;
  const int xcd = f & 7;
  const int rr  = f >> 3;                    // 0..23
  const int bx  = (xcd & 1) * 6 + rr % 6;    // 0..11
  const int by  = (xcd >> 1) * 4 + rr / 6;   // 0..15
  const int m0 = by * 256;
  const int n0 = bx * 256;

  const int srow = lane >> 2;                               // 0..15
  const int scol = ((lane & 3) ^ ((lane >> 3) & 3)) * 8;    // XOR-swz src granule
  const int qsw  = (quad ^ ((l16 >> 1) & 3)) * 8;           // matching read swz

  const bf16* gaBase = A + (size_t)(m0 + wv * 16 + srow) * K + scol;
  const bf16* gbBase = W + (size_t)(n0 + wv * 16 + srow) * K + scol;
  const int ldst = wv * 512 + lane * 8;   // LDS elems; volley 1 adds 4096

#define STG_A(d, kh, kcol)                                                   \
  glds16(&As[d][kh][ldst],        gaBase + (kcol));                          \
  glds16(&As[d][kh][ldst + 4096], gaBase + (size_t)128 * K + (kcol));
#define STG_B(d, kh, kcol)                                                   \
  glds16(&Bs[d][kh][ldst],        gbBase + (kcol));                          \
  glds16(&Bs[d][kh][ldst + 4096], gbBase + (size_t)128 * K + (kcol));

#define RD_PH(d, kh, mh)                                                     \
  _Pragma("unroll") for (int i = 0; i < 4; i++)                              \
    af[i] = *(const bf16x8*)(&As[d][kh][(wm + (mh) * 64 + i * 16 + l16) * 32 + qsw]); \
  _Pragma("unroll") for (int j = 0; j < 4; j++)                              \
    bfr[j] = *(const bf16x8*)(&Bs[d][kh][(wn + j * 16 + l16) * 32 + qsw]);

#define MM_PH(mh)                                                            \
  _Pragma("unroll") for (int i = 0; i < 4; i++)                              \
    _Pragma("unroll") for (int j = 0; j < 4; j++)                            \
      acc[(mh) * 4 + i][j] = __builtin_amdgcn_mfma_f32_16x16x32_bf16(        \
          af[i], bfr[j], acc[(mh) * 4 + i][j], 0, 0, 0);

  floatx4 acc[8][4];
#pragma unroll
  for (int i = 0; i < 8; i++)
#pragma unroll
    for (int j = 0; j < 4; j++) acc[i][j] = (floatx4){0.f, 0.f, 0.f, 0.f};

  // prologue: stage tile 0 (both K-halves) into buf 0
  STG_A(0, 0, 0); STG_B(0, 0, 0);
  STG_A(0, 1, 32); STG_B(0, 1, 32);
  asm volatile("s_waitcnt vmcnt(4)" ::: "memory");   // tile0 kh0 landed
  __builtin_amdgcn_s_barrier();

  const int nt = K >> 6;   // 16
#pragma unroll 1
  for (int t = 0; t < nt; t++) {
    const int c = t & 1;
    const int kn = (t + 1) * 64;
    const bool more = (t + 1 < nt);
    bf16x8 af[4], bfr[4];

    // ---- P0: (kh0, mh0); stage AK0(t+1) ----
    RD_PH(c, 0, 0);
    if (more) { STG_A(c ^ 1, 0, kn); }
    __builtin_amdgcn_s_barrier();
    __builtin_amdgcn_s_setprio(1); MM_PH(0); __builtin_amdgcn_s_setprio(0);

    // ---- P1: (kh0, mh1); stage BK0(t+1); vouch tile t kh1 ----
    RD_PH(c, 0, 1);
    if (more) {
      STG_B(c ^ 1, 0, kn);
      asm volatile("s_waitcnt vmcnt(4)" ::: "memory");
    } else {
      asm volatile("s_waitcnt vmcnt(0)" ::: "memory");
    }
    __builtin_amdgcn_s_barrier();
    __builtin_amdgcn_s_setprio(1); MM_PH(1); __builtin_amdgcn_s_setprio(0);

    // ---- P2: (kh1, mh0); stage AK1(t+1) ----
    RD_PH(c, 1, 0);
    if (more) { STG_A(c ^ 1, 1, kn + 32); }
    __builtin_amdgcn_s_barrier();
    __builtin_amdgcn_s_setprio(1); MM_PH(0); __builtin_amdgcn_s_setprio(0);

    // ---- P3: (kh1, mh1); stage BK1(t+1); vouch tile t+1 kh0 ----
    RD_PH(c, 1, 1);
    if (more) {
      STG_B(c ^ 1, 1, kn + 32);
      asm volatile("s_waitcnt vmcnt(4)" ::: "memory");
    }
    __builtin_amdgcn_s_barrier();
    __builtin_amdgcn_s_setprio(1); MM_PH(1); __builtin_amdgcn_s_setprio(0);
  }

  // ---- epilogue ----
  const int sect = n0 >> 10;                 // 0 = Q, 1 = K, 2 = V
  const int hw   = ((n0 & 1023) + wn) >> 6;  // head for this wave

  float bs[4];
#pragma unroll
  for (int j = 0; j < 4; j++) bs[j] = bias[n0 + wn + j * 16 + l16];

  if (sect < 2) {
    bf16* dst = sect ? Kb : Qb;
    const float qs = sect ? 1.0f : 0.125f;   // fold softmax 1/sqrt(64) into Q (exact 2^-3)
#pragma unroll
    for (int i = 0; i < 8; i++) {
      const int gmBase = m0 + wm + i * 16 + quad * 4;
#pragma unroll
      for (int r = 0; r < 4; r++) {
        const int gm = gmBase + r;
        const int b_ = gm >> 11, t = gm & 2047;
        const size_t rowbase = ((size_t)(b_ * NHEADS + hw) * TSEQ + t) * HDIM;
        const float2 cs0 = rope[t * 32 + l16];
        const float2 cs1 = rope[t * 32 + 16 + l16];
        const float x1a = acc[i][0][r] + bs[0];   // d = l16
        const float x2a = acc[i][2][r] + bs[2];   // d = l16 + 32
        const float x1b = acc[i][1][r] + bs[1];   // d = 16 + l16
        const float x2b = acc[i][3][r] + bs[3];   // d = 48 + l16
        dst[rowbase + l16]      = (bf16)((x1a * cs0.x - x2a * cs0.y) * qs);
        dst[rowbase + 32 + l16] = (bf16)((x1a * cs0.y + x2a * cs0.x) * qs);
        dst[rowbase + 16 + l16] = (bf16)((x1b * cs1.x - x2b * cs1.y) * qs);
        dst[rowbase + 48 + l16] = (bf16)((x1b * cs1.y + x2b * cs1.x) * qs);
      }
    }
  } else {
    // V: store transposed -> Vt[((b*16+h)*64 + d) * TSEQ + t], 8B packed over r
#pragma unroll
    for (int j = 0; j < 4; j++) {
      const int d = j * 16 + l16;
#pragma unroll
      for (int i = 0; i < 8; i++) {
        const int gmBase = m0 + wm + i * 16 + quad * 4;
        const int b_ = gmBase >> 11, t0 = gmBase & 2047;
        bf16x4 vv;
#pragma unroll
        for (int r = 0; r < 4; r++) vv[r] = (bf16)(acc[i][j][r] + bs[j]);
        *(bf16x4*)(Vt + ((size_t)((b_ * NHEADS + hw) * HDIM + d)) * TSEQ + t0) = vv;
      }
    }
  }
}

// ======================================================================
// gemm_out: 128x64 tile, grid 512 = 2 blocks/CU, triple-buffered LDS,
// counted vmcnt(3), XOR-swizzled staging, XCD-chunked swizzle (r4-proven).
// ======================================================================
__global__ __launch_bounds__(256) void gemm_out(
    const bf16* __restrict__ A, const bf16* __restrict__ W,
    const float* __restrict__ bias, float* __restrict__ C,
    int M, int N, int K)
{
  __shared__ bf16 As2[3][128 * 32];
  __shared__ bf16 Bs2[3][64 * 32];

  const int tid  = threadIdx.x;
  const int lane = tid & 63;
  const int wv   = tid >> 6;
  const int quad = lane >> 4;
  const int l16  = lane & 15;

  const int f   = blockIdx.x;
  const int xcd = f & 7;
  const int rr  = f >> 3;                    // 0..63
  const int bx  = (xcd & 1) * 8 + (rr & 7);
  const int by  = (xcd >> 1) * 8 + (rr >> 3);
  const int m0 = by * 128;
  const int n0 = bx * 64;
  const int wm = wv * 32;

  const int srow = lane >> 2;
  const int scol = ((lane & 3) ^ ((lane >> 3) & 3)) * 8;
  const int qsw  = (quad ^ ((l16 >> 1) & 3)) * 8;

  const bf16* ga0 = A + (size_t)(m0 + wv * 32 + srow) * K + scol;
  const bf16* gb0 = W + (size_t)(n0 + wv * 16 + srow) * K + scol;

  floatx4 acc[2][4];
#pragma unroll
  for (int i = 0; i < 2; i++)
#pragma unroll
    for (int j = 0; j < 4; j++) acc[i][j] = (floatx4){0.f, 0.f, 0.f, 0.f};

#define STAGE_O(buf, kk)                                                    \
  glds16(&As2[buf][(wv * 32) * 32], ga0 + (kk));                            \
  glds16(&As2[buf][(wv * 32 + 16) * 32], ga0 + (size_t)16 * K + (kk));      \
  glds16(&Bs2[buf][(wv * 16) * 32], gb0 + (kk));

#define COMPUTE_O(buf)                                                      \
  {                                                                         \
    bf16x8 af[2], bfr[4];                                                   \
    _Pragma("unroll") for (int i = 0; i < 2; i++)                           \
        af[i] = *(const bf16x8*)(&As2[buf][(wm + i * 16 + l16) * 32 + qsw]);\
    _Pragma("unroll") for (int j = 0; j < 4; j++)                           \
        bfr[j] = *(const bf16x8*)(&Bs2[buf][(j * 16 + l16) * 32 + qsw]);    \
    _Pragma("unroll") for (int i = 0; i < 2; i++)                           \
        _Pragma("unroll") for (int j = 0; j < 4; j++)                       \
            acc[i][j] = __builtin_amdgcn_mfma_f32_16x16x32_bf16(            \
                af[i], bfr[j], acc[i][j], 0, 0, 0);                         \
  }

  STAGE_O(0, 0);
  STAGE_O(1, 32);
  int cur = 0;
  const int nsteps = K / 32;
#pragma unroll 1
  for (int t = 0; t < nsteps - 1; t++) {
    asm volatile("s_waitcnt vmcnt(3)" ::: "memory");
    __builtin_amdgcn_s_barrier();
    if (t + 2 < nsteps) {
      const int nb = (cur >= 1) ? cur - 1 : cur + 2;
      STAGE_O(nb, (t + 2) * 32);
    }
    COMPUTE_O(cur);
    cur = (cur == 2) ? 0 : cur + 1;
  }
  asm volatile("s_waitcnt vmcnt(0)" ::: "memory");
  __builtin_amdgcn_s_barrier();
  COMPUTE_O(cur);

#pragma unroll
  for (int i = 0; i < 2; i++) {
    const int gmBase = m0 + wm + i * 16 + quad * 4;
#pragma unroll
    for (int j = 0; j < 4; j++) {
      const int gn = n0 + j * 16 + l16;
      const float bsv = bias[gn];
#pragma unroll
      for (int r = 0; r < 4; r++)
        C[(size_t)(gmBase + r) * N + gn] = acc[i][j][r] + bsv;
    }
  }
}

// ---- XOR granule swizzle for staging (reads lane-linear, conflict-free) ----
__device__ inline int swz(int g) { return (g & ~7) | ((g ^ (g >> 3) ^ (g >> 6)) & 7); }

// ======================================================================
// Flash attention v10 (r12 best-measured): v7 structure + uniform causal
// chunk classes + pre-scaled Q.
// ======================================================================
__global__ __launch_bounds__(512) void attn_kernel(
    const bf16* __restrict__ Q, const bf16* __restrict__ K,
    const bf16* __restrict__ Vt, bf16* __restrict__ O,
    const int* __restrict__ ids, const int* __restrict__ gidx)
{
  __shared__ bf16 Ks[2][4096];
  __shared__ bf16 Vs[2][4096];
  __shared__ int flags[8];

  const int tid  = threadIdx.x;
  const int lane = tid & 63;
  const int wv   = tid >> 6;    // 0..7
  const int gg   = wv >> 2;     // key-half group
  const int w4   = wv & 3;      // row group (16 q-rows)
  const int quad = lane >> 4;
  const int l16  = lane & 15;

  const int xcd = blockIdx.x & 7;
  const int j   = blockIdx.x >> 3;
  const int bh  = xcd * 4 + (j >> 4);
  const int p   = j & 15;
  const int b  = bh >> 4;
  const int h  = bh & 15;

  const bf16* Qp = Q + (size_t)bh * TSEQ * HDIM;
  const bf16* Kp = K + (size_t)bh * TSEQ * HDIM;
  const bf16* Vp = Vt + (size_t)bh * HDIM * TSEQ;

  const int rK2 = tid >> 3, dcK = tid & 7;
  const int rKl = rK2 & 31, khi = rK2 >> 5;
  const int gk = ((rKl >> 2) & 1) * 128 + (dcK >> 2) * 64 +
                 ((dcK & 3) * 16 + (((rKl >> 3) << 2) | (rKl & 3)));
  const int kd = swz(gk + khi * 256) * 8;
  const int dV = tid >> 3, uV = tid & 7;
  const int gv = (uV >> 2) * 256 + (dV >> 4) * 64 + ((uV & 3) * 16 + (dV & 15));
  const int vd = swz(gv) * 8;

  const int g0v = gidx[0], g1v = gidx[1], g2v = gidx[2];

#pragma unroll
  for (int ph = 0; ph < 2; ph++) {
    const int qt = ph ? p : (31 - p);
    const int q0 = qt * 64 + w4 * 16;
    const int kfull = qt * 64;   // chunks strictly below: unmasked for all lanes

    const bf16x8 qf0 = *(const bf16x8*)(Qp + (size_t)(q0 + l16) * HDIM + quad * 8);
    const bf16x8 qf1 = *(const bf16x8*)(Qp + (size_t)(q0 + l16) * HDIM + 32 + quad * 8);

    const int myq = q0 + l16;
    const int myid = ids[b * TSEQ + myq];
    const int gl = (myid == g0v) | (myid == g1v) | (myid == g2v);
    flags[wv] = __any(gl);
    __syncthreads();
    int anyg = 0;
#pragma unroll
    for (int i2 = 0; i2 < 8; i2++) anyg |= flags[i2];
    const int kmax = anyg ? TSEQ : (qt * 64 + 64);

    float lsum = 0.f;
    floatx4 o[4];
#pragma unroll
    for (int nt = 0; nt < 4; nt++) o[nt] = (floatx4){0.f, 0.f, 0.f, 0.f};

    bf16x8 kA = *(const bf16x8*)(Kp + tid * 8);
    bf16x8 vA = *(const bf16x8*)(Vp + (size_t)dV * TSEQ + uV * 8);

    for (int k0 = 0; k0 < kmax; k0 += 64) {
      bf16* KsB = Ks[(k0 >> 6) & 1];
      bf16* VsB = Vs[(k0 >> 6) & 1];
      *(bf16x8*)(KsB + kd) = kA;
      *(bf16x8*)(VsB + vd) = vA;
      __syncthreads();

      if (k0 + 64 < kmax) {
        kA = *(const bf16x8*)(Kp + (size_t)(k0 + 64) * HDIM + tid * 8);
        vA = *(const bf16x8*)(Vp + (size_t)dV * TSEQ + k0 + 64 + uV * 8);
      }

      const int kb = k0 + gg * 32;
      const int rb = gg * 256 + lane;
      const bf16x8 a00 = *(const bf16x8*)(KsB + swz(rb) * 8);
      const bf16x8 a01 = *(const bf16x8*)(KsB + swz(rb + 64) * 8);
      const bf16x8 a10 = *(const bf16x8*)(KsB + swz(rb + 128) * 8);
      const bf16x8 a11 = *(const bf16x8*)(KsB + swz(rb + 192) * 8);
      floatx4 s0 = (floatx4){0.f, 0.f, 0.f, 0.f};
      floatx4 s1 = (floatx4){0.f, 0.f, 0.f, 0.f};
      s0 = __builtin_amdgcn_mfma_f32_16x16x32_bf16(a00, qf0, s0, 0, 0, 0);
      s0 = __builtin_amdgcn_mfma_f32_16x16x32_bf16(a01, qf1, s0, 0, 0, 0);
      s1 = __builtin_amdgcn_mfma_f32_16x16x32_bf16(a10, qf0, s1, 0, 0, 0);
      s1 = __builtin_amdgcn_mfma_f32_16x16x32_bf16(a11, qf1, s1, 0, 0, 0);

      bf16x8 pf;
      if (k0 < kfull) {
#pragma unroll
        for (int r = 0; r < 4; r++) {
          const float p0 = __expf(s0[r]);
          const float p1 = __expf(s1[r]);
          lsum += p0 + p1;
          pf[r]     = (bf16)p0;
          pf[4 + r] = (bf16)p1;
        }
      } else if (k0 == kfull) {
#pragma unroll
        for (int r = 0; r < 4; r++) {
          const int key0 = kb + quad * 8 + r;
          const int key1 = key0 + 4;
          const float p0 = (gl || key0 <= myq) ? __expf(s0[r]) : 0.f;
          const float p1 = (gl || key1 <= myq) ? __expf(s1[r]) : 0.f;
          lsum += p0 + p1;
          pf[r]     = (bf16)p0;
          pf[4 + r] = (bf16)p1;
        }
      } else {
#pragma unroll
        for (int r = 0; r < 4; r++) {
          const float p0 = gl ? __expf(s0[r]) : 0.f;
          const float p1 = gl ? __expf(s1[r]) : 0.f;
          lsum += p0 + p1;
          pf[r]     = (bf16)p0;
          pf[4 + r] = (bf16)p1;
        }
      }

#pragma unroll
      for (int nt = 0; nt < 4; nt++) {
        const bf16x8 vf = *(const bf16x8*)(VsB + swz(gg * 256 + nt * 64 + lane) * 8);
        o[nt] = __builtin_amdgcn_mfma_f32_16x16x32_bf16(pf, vf, o[nt], 0, 0, 0);
      }
    }

    lsum += __shfl_xor(lsum, 16);
    lsum += __shfl_xor(lsum, 32);

    __syncthreads();
    float* osc = (float*)Ks;
    float* lsc = (float*)Vs;
    const int rbase = (w4 * 64 + lane) * 16;
    if (gg == 1) {
#pragma unroll
      for (int nt = 0; nt < 4; nt++)
        *(floatx4*)&osc[rbase + ((nt ^ (lane & 3)) * 4)] = o[nt];
      lsc[w4 * 64 + lane] = lsum;
    }
    __syncthreads();
    if (gg == 0) {
      lsum += lsc[w4 * 64 + lane];
#pragma unroll
      for (int nt = 0; nt < 4; nt++)
        o[nt] += *(const floatx4*)&osc[rbase + ((nt ^ (lane & 3)) * 4)];

#pragma unroll
      for (int r = 0; r < 4; r++) {
        const float inv = 1.0f / __shfl(lsum, quad * 4 + r);
        const int q = q0 + quad * 4 + r;
        const size_t rowoff = ((size_t)b * TSEQ + q) * HIDDEN + h * HDIM;
#pragma unroll
        for (int nt = 0; nt < 4; nt++)
          O[rowoff + nt * 16 + l16] = (bf16)(o[nt][r] * inv);
      }
    }
    __syncthreads();
  }
}

// ======================================================================
extern "C" void kernel_launch(void* const* d_in, const int* in_sizes, int n_in,
                              void* d_out, int out_size, void* d_ws, size_t ws_size,
                              hipStream_t stream)
{
  const float* x     = (const float*)d_in[0];
  const int*   ids   = (const int*)d_in[1];
  const float* qkv_w = (const float*)d_in[2];
  const float* qkv_b = (const float*)d_in[3];
  const float* out_w = (const float*)d_in[4];
  const float* out_b = (const float*)d_in[5];
  const int*   gidx  = (const int*)d_in[6];
  float* out = (float*)d_out;

  // ws layout: Q@0, K@8M, Vt@16M, slot24@24M (xb -> O).  When ws_size
  // allows (observed 256 MiB via harness poison fills), out_wb lives at
  // ws+32M, written by prep (fused cvt) — one fewer kernel launch.
  // Fallback (ws_size < 34 MiB): out_wb at ws+16M via separate cvt after
  // attn (r12-proven path).  qkv_wb (6 MiB) in d_out (dead until gemm_out
  // overwrites); rope table at d_out+6M (dead after gemm_qkv).
  char* ws = (char*)d_ws;
  bf16* Q      = (bf16*)(ws);
  bf16* Kb     = (bf16*)(ws + (size_t)(8u << 20));
  bf16* Vt     = (bf16*)(ws + (size_t)(16u << 20));
  bf16* slot24 = (bf16*)(ws + (size_t)(24u << 20));
  bf16* xb     = slot24;
  bf16* O      = slot24;
  bf16* qkv_wb = (bf16*)d_out;
  float2* rope = (float2*)((char*)d_out + (size_t)(6u << 20));

  const bool big_ws = ws_size >= ((size_t)34u << 20);
  bf16* out_wb = big_ws ? (bf16*)(ws + (size_t)(32u << 20))
                        : (bf16*)(ws + (size_t)(16u << 20));

  // 0) convert x + qkv_w (+ out_w when big_ws), build rope table
  prep_kernel<<<big_ws ? 4160 : 3648, 256, 0, stream>>>(
      x, xb, qkv_w, qkv_wb, rope, out_w, out_wb);
  // 1) QKV projection -> Q (RoPE'd + 0.125-scaled) / K (RoPE'd) + Vt
  gemm_qkv<<<192, 512, 0, stream>>>(
      xb, qkv_wb, qkv_b, rope, Q, Kb, Vt, MTOT, 3 * HIDDEN, HIDDEN);
  // 2) attention -> O (b,t,hidden) in slot24 (xb dead)
  attn_kernel<<<512, 512, 0, stream>>>(Q, Kb, Vt, O, ids, gidx);
  // 3) fallback only: convert out_w (overwrites Vt, dead)
  if (!big_ws)
    cvt_f32_bf16<<<512, 256, 0, stream>>>(out_w, out_wb, HIDDEN * HIDDEN);
  // 4) output projection -> d_out (overwrites qkv_wb + rope, dead)
  gemm_out<<<512, 256, 0, stream>>>(
      O, out_wb, out_b, out, MTOT, HIDDEN, HIDDEN);
}